// Round 1
// baseline (843.173 us; speedup 1.0000x reference)
//
#include <hip/hip_runtime.h>
#include <hip/hip_bf16.h>
#include <math.h>

#define S_LEN 4096
#define DMODEL 768
#define NHEADS 12
#define DH 64
#define FDIM 3072
#define NEXP 7
#define NPAIR (2*S_LEN)
#define MAXTILES 40

typedef __bf16 bf16x8 __attribute__((ext_vector_type(8)));
typedef float f32x4 __attribute__((ext_vector_type(4)));

__device__ __forceinline__ unsigned short f2bf(float f){
  union { float f; unsigned u; } v; v.f = f;
  unsigned r = v.u + 0x7fffu + ((v.u >> 16) & 1u);
  return (unsigned short)(r >> 16);
}
__device__ __forceinline__ float bf2f(unsigned short h){
  union { unsigned u; float f; } v; v.u = ((unsigned)h) << 16;
  return v.f;
}
__device__ __forceinline__ float gelu_f(float x){
  return 0.5f * x * (1.0f + erff(x * 0.7071067811865475f));
}
__device__ __forceinline__ f32x4 mfma16(bf16x8 a, bf16x8 b, f32x4 c){
  return __builtin_amdgcn_mfma_f32_16x16x32_bf16(a, b, c, 0, 0, 0);
}
// async global->LDS, 16 B per lane. LDS side must be wave-uniform base + lane*16.
__device__ __forceinline__ void glds16(const void* g, void* l){
  __builtin_amdgcn_global_load_lds((const __attribute__((address_space(1))) unsigned*)g,
                                   (__attribute__((address_space(3))) unsigned*)l, 16, 0, 0);
}

// ---------------- elementwise fp32 -> bf16 hi/lo split ----------------
__global__ __launch_bounds__(256) void split_kernel(const float* __restrict__ in,
    unsigned short* __restrict__ hi, unsigned short* __restrict__ lo, int n){
  int i = blockIdx.x*256 + threadIdx.x;
  if (i >= n) return;
  float v = in[i];
  unsigned short h = f2bf(v);
  hi[i] = h;
  lo[i] = f2bf(v - bf2f(h));
}

// ---------------- tiled transpose + convert: in [mat][R][C] f32 -> out [mat][C][R] bf16 (hi[,lo]) ----------------
template<int SPLIT>
__global__ __launch_bounds__(256) void transp_kernel(const float* __restrict__ in,
    unsigned short* __restrict__ hi, unsigned short* __restrict__ lo,
    int R, int C, long inStride, long outStride){
  const float* ip = in + (long)blockIdx.z * inStride;
  long ob = (long)blockIdx.z * outStride;
  __shared__ float tile[32][33];
  int c0 = blockIdx.x*32, r0 = blockIdx.y*32;
  int tx = threadIdx.x, ty = threadIdx.y;
  for (int i = ty; i < 32; i += 8)
    tile[i][tx] = ip[(long)(r0+i)*C + c0 + tx];
  __syncthreads();
  int t  = tx + ty*32;
  int sx = t & 15;        // r-pair index
  int sc = t >> 4;        // col group
  #pragma unroll
  for (int j = 0; j < 2; j++){
    int cc = sc + j*16;
    float v0 = tile[sx*2][cc], v1 = tile[sx*2+1][cc];
    long oidx = ob + (long)(c0+cc)*R + r0 + sx*2;
    unsigned uh = (unsigned)f2bf(v0) | ((unsigned)f2bf(v1) << 16);
    *(unsigned*)(hi + oidx) = uh;
    if (SPLIT){
      unsigned ul = (unsigned)f2bf(v0 - bf2f(f2bf(v0))) | ((unsigned)f2bf(v1 - bf2f(f2bf(v1))) << 16);
      *(unsigned*)(lo + oidx) = ul;
    }
  }
}

// ---------------- generic 128x128x32 bf16 MFMA GEMM, B^T ("Bt[n][k]") layout ----------------
// MODE: 0=QKV  1=WO  4=WD
struct GemmP {
  const unsigned short* A;
  const unsigned short* Alo;
  const unsigned short* B;
  const unsigned short* Blo;
  int M, N, K;
  const float* bias;  const float* bias2; const float* bias3;
  const float* resid;
  float* outF;
  unsigned short* outBF;
  unsigned short *qhi,*qlo,*khi,*klo,*vthi,*vtlo;
  const int* pair_token;
  const float* pair_w;
  const int* cnt;
  const int* offs;
  const int* tile_e;
  const int* tile_m;
  const int* ntiles;
};

template<int MODE, int PLANES>
__global__ __launch_bounds__(256, 2) void gemm_bt(GemmP p){
  const int tid  = threadIdx.x;
  const int lane = tid & 63;
  const int wave = tid >> 6;
  const int quad = lane >> 4;
  const int ln   = lane & 15;
  const int wr = wave >> 1, wc = wave & 1;
  const int bn0 = blockIdx.x * 128;
  const int bm0 = blockIdx.y * 128;
  const int K = p.K;

  long aoff[2]; long boff[2]; int koff[2];
  #pragma unroll
  for (int j = 0; j < 2; j++){
    int c = tid + j*256;
    int row = c >> 2;
    koff[j] = (c & 3) * 8;
    aoff[j] = (long)(bm0 + row) * K;
    boff[j] = (long)(bn0 + row) * K;
  }

  // double-buffered stages: prefetch pipeline (issue next-tile loads before compute)
  __shared__ __align__(16) unsigned short As[2][PLANES][128*32];
  __shared__ __align__(16) unsigned short Bs[2][PLANES][128*32];

  auto stage = [&](int k0, int buf){
    #pragma unroll
    for (int j = 0; j < 2; j++){
      int c = tid + j*256;
      glds16(p.A + aoff[j] + k0 + koff[j], &As[buf][0][c*8]);
      glds16(p.B + boff[j] + k0 + koff[j], &Bs[buf][0][c*8]);
      if (PLANES == 2){
        glds16(p.Alo + aoff[j] + k0 + koff[j], &As[buf][1][c*8]);
        glds16(p.Blo + boff[j] + k0 + koff[j], &Bs[buf][1][c*8]);
      }
    }
  };

  f32x4 zero4 = {0.f, 0.f, 0.f, 0.f};
  f32x4 acc[4][4];
  #pragma unroll
  for (int i = 0; i < 4; i++)
    #pragma unroll
    for (int j = 0; j < 4; j++) acc[i][j] = zero4;

  stage(0, 0);
  __syncthreads();          // drains vmcnt(0): tile 0 resident
  int cur = 0;

  for (int k0 = 0; k0 < K; k0 += 32){
    if (k0 + 32 < K) stage(k0 + 32, cur ^ 1);   // issue-early: hides under compute
    bf16x8 af[PLANES][4], bfr[PLANES][4];
    #pragma unroll
    for (int mt = 0; mt < 4; mt++)
      #pragma unroll
      for (int pl = 0; pl < PLANES; pl++)
        af[pl][mt] = *(const bf16x8*)&As[cur][pl][(wr*64 + mt*16 + ln)*32 + quad*8];
    #pragma unroll
    for (int nt = 0; nt < 4; nt++)
      #pragma unroll
      for (int pl = 0; pl < PLANES; pl++)
        bfr[pl][nt] = *(const bf16x8*)&Bs[cur][pl][(wc*64 + nt*16 + ln)*32 + quad*8];
    #pragma unroll
    for (int mt = 0; mt < 4; mt++){
      #pragma unroll
      for (int nt = 0; nt < 4; nt++){
        acc[mt][nt] = mfma16(af[0][mt], bfr[0][nt], acc[mt][nt]);
        if (PLANES == 2){
          acc[mt][nt] = mfma16(af[0][mt], bfr[1][nt], acc[mt][nt]);
          acc[mt][nt] = mfma16(af[1][mt], bfr[0][nt], acc[mt][nt]);
        }
      }
    }
    __syncthreads();        // drains vmcnt(0) (next tile landed) + lgkm; protects buffer reuse
    cur ^= 1;
  }

  #pragma unroll
  for (int mt = 0; mt < 4; mt++){
    #pragma unroll
    for (int nt = 0; nt < 4; nt++){
      #pragma unroll
      for (int r = 0; r < 4; r++){
        int gm = bm0 + wr*64 + mt*16 + quad*4 + r;
        int gn = bn0 + wc*64 + nt*16 + ln;
        float v = acc[mt][nt][r];
        if (MODE == 0){
          int which = gn >= 1536 ? 2 : (gn >= 768 ? 1 : 0);
          int nn = gn - which*768;
          int hh = nn >> 6, dh = nn & 63;
          if (which == 0){
            float q = (v + p.bias[nn]) * 0.125f;
            unsigned short qh = f2bf(q);
            long o = ((long)hh*S_LEN + gm)*64 + dh;
            p.qhi[o] = qh; p.qlo[o] = f2bf(q - bf2f(qh));
          } else if (which == 1){
            float kv = v + p.bias2[nn];
            unsigned short kh = f2bf(kv);
            long o = ((long)hh*S_LEN + gm)*64 + dh;
            p.khi[o] = kh; p.klo[o] = f2bf(kv - bf2f(kh));
          } else {
            float vv = v + p.bias3[nn];
            unsigned short vh = f2bf(vv);
            long o = ((long)hh*64 + dh)*S_LEN + gm;   // V^T: [h][d][s]
            p.vthi[o] = vh; p.vtlo[o] = f2bf(vv - bf2f(vh));
          }
        } else if (MODE == 1 || MODE == 4){
          long i = (long)gm*DMODEL + gn;
          p.outF[i] = v + p.bias[gn] + p.resid[i];
        }
      }
    }
  }
}

// ---------------- 256M x 128N MoE GEMM, 512 threads / 8 waves, PLANES=1 ----------------
// Compacted tile list (blockIdx.y -> (expert, m0)) + double-buffered prefetch pipeline.
// MODE: 2=MOE1(gather A by pair_token)  3=MOE2(contiguous pair rows)
template<int MODE>
__global__ __launch_bounds__(512, 4) void gemm_big(GemmP p){
  const int ty = blockIdx.y;
  if (ty >= *p.ntiles) return;
  const int e   = p.tile_e[ty];
  const int bm0 = p.tile_m[ty];

  const int tid  = threadIdx.x;
  const int lane = tid & 63;
  const int wave = tid >> 6;          // 0..7, 4x2 (wr x wc)
  const int quad = lane >> 4;
  const int ln   = lane & 15;
  const int wr = wave >> 1, wc = wave & 1;
  const int bn0 = blockIdx.x * 128;
  const int K = p.K;

  const int eoff = p.offs[e];
  const int Mloc = p.cnt[e];
  const unsigned short* Bp = p.B + (long)e * FDIM * DMODEL;

  long aoff[2]; int koffA[2];
  #pragma unroll
  for (int j = 0; j < 2; j++){
    int c = tid + j*512;
    int row = c >> 2;
    koffA[j] = (c & 3) * 8;
    int r = bm0 + row; if (r >= Mloc) r = Mloc - 1;
    aoff[j] = (MODE == 2) ? (long)p.pair_token[eoff + r] * K : (long)(eoff + r) * K;
  }
  long boff; int koffB;
  {
    int row = tid >> 2;
    koffB = (tid & 3) * 8;
    boff = (long)(bn0 + row) * K;
  }

  __shared__ __align__(16) unsigned short As[2][256*32];
  __shared__ __align__(16) unsigned short Bs[2][128*32];

  auto stage = [&](int k0, int buf){
    #pragma unroll
    for (int j = 0; j < 2; j++){
      int c = tid + j*512;
      glds16(p.A + aoff[j] + k0 + koffA[j], &As[buf][c*8]);
    }
    glds16(Bp + boff + k0 + koffB, &Bs[buf][tid*8]);
  };

  f32x4 zero4 = {0.f, 0.f, 0.f, 0.f};
  f32x4 acc[4][4];
  #pragma unroll
  for (int i = 0; i < 4; i++)
    #pragma unroll
    for (int j = 0; j < 4; j++) acc[i][j] = zero4;

  stage(0, 0);
  __syncthreads();
  int cur = 0;

  for (int k0 = 0; k0 < K; k0 += 32){
    if (k0 + 32 < K) stage(k0 + 32, cur ^ 1);
    bf16x8 af[4], bfr[4];
    #pragma unroll
    for (int mt = 0; mt < 4; mt++)
      af[mt] = *(const bf16x8*)&As[cur][(wr*64 + mt*16 + ln)*32 + quad*8];
    #pragma unroll
    for (int nt = 0; nt < 4; nt++)
      bfr[nt] = *(const bf16x8*)&Bs[cur][(wc*64 + nt*16 + ln)*32 + quad*8];
    #pragma unroll
    for (int mt = 0; mt < 4; mt++)
      #pragma unroll
      for (int nt = 0; nt < 4; nt++)
        acc[mt][nt] = mfma16(af[mt], bfr[nt], acc[mt][nt]);
    __syncthreads();
    cur ^= 1;
  }

  #pragma unroll
  for (int mt = 0; mt < 4; mt++){
    #pragma unroll
    for (int nt = 0; nt < 4; nt++){
      #pragma unroll
      for (int r = 0; r < 4; r++){
        int gm = bm0 + wr*64 + mt*16 + quad*4 + r;
        int gn = bn0 + wc*64 + nt*16 + ln;
        if (gm < Mloc){
          float v = acc[mt][nt][r];
          if (MODE == 2){
            v = gelu_f(v + p.bias[(long)e*FDIM + gn]);
            p.outBF[(long)(eoff + gm)*FDIM + gn] = f2bf(v);
          } else {
            int pi = eoff + gm;
            p.outF[(long)pi*DMODEL + gn] = v + p.bias[(long)e*DMODEL + gn];
          }
        }
      }
    }
  }
}

// ---------------- MFMA sliding-window attention, split bf16 hi/lo (fp32-grade) ----------------
// grid (16 chunks, 12 heads, 4 strips of 64 q); block 256 (4 waves x 16-q sub-strip)
__global__ __launch_bounds__(256) void attn_mfma(
    const unsigned short* __restrict__ Qhi, const unsigned short* __restrict__ Qlo,
    const unsigned short* __restrict__ Khi, const unsigned short* __restrict__ Klo,
    const unsigned short* __restrict__ Vthi, const unsigned short* __restrict__ Vtlo,
    unsigned short* __restrict__ attn_hi, unsigned short* __restrict__ attn_lo){
  const int c = blockIdx.x, h = blockIdx.y, qb = blockIdx.z;
  const int tid = threadIdx.x;
  const int lane = tid & 63, w = tid >> 6;
  const int quad = lane >> 4, ln = lane & 15;
  const int q0 = c*256 + qb*64;
  const int qw = q0 + w*16;

  __shared__ __align__(16) unsigned short KsH[64*64], KsL[64*64];
  __shared__ __align__(16) unsigned short VsH[64*64], VsL[64*64];
  __shared__ __align__(16) unsigned short PsH[4][16*72], PsL[4][16*72];

  bf16x8 qf_h[2], qf_l[2];
  {
    long qrow = ((long)h*S_LEN + qw + ln)*64 + quad*8;
    qf_h[0] = *(const bf16x8*)(Qhi + qrow);
    qf_h[1] = *(const bf16x8*)(Qhi + qrow + 32);
    qf_l[0] = *(const bf16x8*)(Qlo + qrow);
    qf_l[1] = *(const bf16x8*)(Qlo + qrow + 32);
  }

  float m_s[4], l_s[4];
  f32x4 Oc[4];
  f32x4 z4 = {0.f,0.f,0.f,0.f};
  #pragma unroll
  for (int r = 0; r < 4; r++){ m_s[r] = -1e30f; l_s[r] = 0.f; }
  #pragma unroll
  for (int nt = 0; nt < 4; nt++) Oc[nt] = z4;

  const unsigned short* KhiB = Khi + (long)h*S_LEN*64;
  const unsigned short* KloB = Klo + (long)h*S_LEN*64;
  const unsigned short* VhiB = Vthi + (long)h*64*S_LEN;
  const unsigned short* VloB = Vtlo + (long)h*64*S_LEN;

  for (int kb = 0; kb < 12; kb++){
    const int kstart = c*256 - 256 + kb*64;
    if (kstart + 63 < 0 || kstart >= S_LEN) continue;
    if (kstart + 63 < q0 - 256 || kstart > q0 + 63 + 256) continue;
    __syncthreads();
    #pragma unroll
    for (int p2 = 0; p2 < 2; p2++){
      int idx = p2*256 + tid;
      int row = idx >> 3;
      int pc  = idx & 7;
      int lc  = pc ^ (row & 7);
      int ka = kstart + row;
      int kac = ka < 0 ? 0 : (ka > S_LEN-1 ? S_LEN-1 : ka);
      long gK = (long)kac*64 + lc*8;
      glds16(KhiB + gK, &KsH[idx*8]);
      glds16(KloB + gK, &KsL[idx*8]);
      int ks0 = kstart + lc*8;
      ks0 = ks0 < 0 ? 0 : (ks0 > S_LEN-8 ? S_LEN-8 : ks0);
      long gV = (long)row*S_LEN + ks0;
      glds16(VhiB + gV, &VsH[idx*8]);
      glds16(VloB + gV, &VsL[idx*8]);
    }
    __syncthreads();
    if (kstart + 63 < qw - 256 || kstart > qw + 15 + 256) continue;

    f32x4 Sc[4];
    #pragma unroll
    for (int nt = 0; nt < 4; nt++) Sc[nt] = z4;
    #pragma unroll
    for (int kc = 0; kc < 2; kc++){
      bf16x8 bh[4], bl[4];
      #pragma unroll
      for (int nt = 0; nt < 4; nt++){
        int row = nt*16 + ln;
        int o = row*64 + (((kc*4 + quad) ^ (row & 7))*8);
        bh[nt] = *(const bf16x8*)&KsH[o];
        bl[nt] = *(const bf16x8*)&KsL[o];
      }
      #pragma unroll
      for (int nt = 0; nt < 4; nt++){
        Sc[nt] = mfma16(qf_h[kc], bh[nt], Sc[nt]);
        Sc[nt] = mfma16(qf_h[kc], bl[nt], Sc[nt]);
        Sc[nt] = mfma16(qf_l[kc], bh[nt], Sc[nt]);
      }
    }
    bool interior = (kstart >= qw - 241) && (kstart <= qw + 193) &&
                    (kstart >= 0) && (kstart + 63 <= S_LEN - 1);
    if (!interior){
      #pragma unroll
      for (int nt = 0; nt < 4; nt++){
        int ka = kstart + nt*16 + ln;
        #pragma unroll
        for (int r = 0; r < 4; r++){
          int qa = qw + quad*4 + r;
          bool v = (ka >= 0) && (ka < S_LEN) && (ka >= qa - 256) && (ka <= qa + 256);
          if (!v) Sc[nt][r] = -3.0e38f;
        }
      }
    }
    float bm[4];
    #pragma unroll
    for (int r = 0; r < 4; r++)
      bm[r] = fmaxf(fmaxf(Sc[0][r], Sc[1][r]), fmaxf(Sc[2][r], Sc[3][r]));
    #pragma unroll
    for (int off = 1; off < 16; off <<= 1)
      #pragma unroll
      for (int r = 0; r < 4; r++) bm[r] = fmaxf(bm[r], __shfl_xor(bm[r], off));
    float al[4];
    #pragma unroll
    for (int r = 0; r < 4; r++){
      float mnew = fmaxf(m_s[r], bm[r]);
      al[r] = __expf(m_s[r] - mnew);
      m_s[r] = mnew;
    }
    float psum[4] = {0.f,0.f,0.f,0.f};
    #pragma unroll
    for (int nt = 0; nt < 4; nt++){
      #pragma unroll
      for (int r = 0; r < 4; r++){
        float pv = __expf(Sc[nt][r] - m_s[r]);
        psum[r] += pv;
        unsigned short ph = f2bf(pv);
        int o = (quad*4 + r)*72 + nt*16 + ln;
        PsH[w][o] = ph;
        PsL[w][o] = f2bf(pv - bf2f(ph));
      }
    }
    #pragma unroll
    for (int off = 1; off < 16; off <<= 1)
      #pragma unroll
      for (int r = 0; r < 4; r++) psum[r] += __shfl_xor(psum[r], off);
    #pragma unroll
    for (int r = 0; r < 4; r++) l_s[r] = l_s[r]*al[r] + psum[r];
    #pragma unroll
    for (int nt = 0; nt < 4; nt++)
      #pragma unroll
      for (int r = 0; r < 4; r++) Oc[nt][r] *= al[r];
    asm volatile("s_waitcnt lgkmcnt(0)" ::: "memory");
    #pragma unroll
    for (int kc = 0; kc < 2; kc++){
      bf16x8 ph = *(const bf16x8*)&PsH[w][ln*72 + kc*32 + quad*8];
      bf16x8 pl = *(const bf16x8*)&PsL[w][ln*72 + kc*32 + quad*8];
      #pragma unroll
      for (int nt = 0; nt < 4; nt++){
        int row = nt*16 + ln;
        int o = row*64 + (((kc*4 + quad) ^ (row & 7))*8);
        bf16x8 vh = *(const bf16x8*)&VsH[o];
        bf16x8 vl = *(const bf16x8*)&VsL[o];
        Oc[nt] = mfma16(ph, vh, Oc[nt]);
        Oc[nt] = mfma16(ph, vl, Oc[nt]);
        Oc[nt] = mfma16(pl, vh, Oc[nt]);
      }
    }
  }
  float inv[4];
  #pragma unroll
  for (int r = 0; r < 4; r++) inv[r] = 1.f / l_s[r];
  #pragma unroll
  for (int nt = 0; nt < 4; nt++){
    #pragma unroll
    for (int r = 0; r < 4; r++){
      int qa = qw + quad*4 + r;
      long o = (long)qa*DMODEL + h*64 + nt*16 + ln;
      float ov = Oc[nt][r] * inv[r];
      unsigned short oh = f2bf(ov);
      attn_hi[o] = oh;
      attn_lo[o] = f2bf(ov - bf2f(oh));
    }
  }
}

// ---------------- LayerNorm (fp32), optional bf16 copy ----------------
__global__ __launch_bounds__(256) void ln_kernel(const float* __restrict__ x,
    const float* __restrict__ g, const float* __restrict__ b,
    float* __restrict__ outF, unsigned short* __restrict__ outBF){
  int s = blockIdx.x;
  const float* row = x + (long)s*DMODEL;
  int t = threadIdx.x;
  float v0 = row[t], v1 = row[t+256], v2 = row[t+512];
  float sum = v0+v1+v2;
  float sq  = v0*v0 + v1*v1 + v2*v2;
  for (int o = 32; o > 0; o >>= 1){ sum += __shfl_xor(sum, o); sq += __shfl_xor(sq, o); }
  __shared__ float s1[4], s2[4];
  int wv = t >> 6;
  if ((t & 63) == 0){ s1[wv] = sum; s2[wv] = sq; }
  __syncthreads();
  sum = s1[0]+s1[1]+s1[2]+s1[3];
  sq  = s2[0]+s2[1]+s2[2]+s2[3];
  float mean = sum * (1.0f/DMODEL);
  float var  = sq  * (1.0f/DMODEL) - mean*mean;
  float inv = rsqrtf(var + 1e-5f);
  float* orow = outF + (long)s*DMODEL;
  unsigned short* brow = outBF ? outBF + (long)s*DMODEL : (unsigned short*)0;
  #pragma unroll
  for (int j = 0; j < 3; j++){
    int d = t + j*256;
    float y = (row[d] - mean) * inv * g[d] + b[d];
    orow[d] = y;
    if (brow) brow[d] = f2bf(y);
  }
}

// ---------------- gate: fp32 logits, top-2, softmax, routing records ----------------
__global__ __launch_bounds__(64) void gate_kernel(const float* __restrict__ x,
    const float* __restrict__ gw, const float* __restrict__ gb,
    float* __restrict__ gate_out, int* __restrict__ tok_e,
    float* __restrict__ tok_w, int* __restrict__ cnt){
  int s = blockIdx.x;
  int lane = threadIdx.x;
  float acc[NEXP];
  #pragma unroll
  for (int e = 0; e < NEXP; e++) acc[e] = 0.f;
  const float* xr = x + (long)s*DMODEL;
  for (int d = lane; d < DMODEL; d += 64){
    float xv = xr[d];
    const float* wr = gw + (long)d*NEXP;
    #pragma unroll
    for (int e = 0; e < NEXP; e++) acc[e] += xv * wr[e];
  }
  #pragma unroll
  for (int e = 0; e < NEXP; e++){
    float v = acc[e];
    for (int o = 32; o > 0; o >>= 1) v += __shfl_xor(v, o);
    acc[e] = v;
  }
  if (lane == 0){
    #pragma unroll
    for (int e = 0; e < NEXP; e++) acc[e] += gb[e];
    int i0 = 0;
    for (int e = 1; e < NEXP; e++) if (acc[e] > acc[i0]) i0 = e;
    int i1 = -1;
    for (int e = 0; e < NEXP; e++) if (e != i0 && (i1 < 0 || acc[e] > acc[i1])) i1 = e;
    float e1 = expf(acc[i1] - acc[i0]);
    float inv = 1.f / (1.f + e1);
    float w0 = inv, w1 = e1 * inv;
    float* go = gate_out + (long)s*NEXP;
    #pragma unroll
    for (int e = 0; e < NEXP; e++) go[e] = 0.f;
    go[i0] = w0; go[i1] = w1;
    tok_e[s*2] = i0; tok_e[s*2+1] = i1;
    tok_w[s*2] = w0; tok_w[s*2+1] = w1;
    atomicAdd(&cnt[i0], 1);
    atomicAdd(&cnt[i1], 1);
  }
}

// scan + compacted tile list: tiles = (expert, m0) pairs with m0 < cnt[e], step 256
__global__ void scan_kernel(const int* __restrict__ cnt, int* __restrict__ offs,
                            int* __restrict__ tile_e, int* __restrict__ tile_m,
                            int* __restrict__ ntiles){
  if (threadIdx.x == 0 && blockIdx.x == 0){
    int s = 0, t = 0;
    for (int e = 0; e < NEXP; e++){
      offs[e] = s;
      for (int m0 = 0; m0 < cnt[e]; m0 += 256){
        tile_e[t] = e; tile_m[t] = m0; t++;
      }
      s += cnt[e];
    }
    *ntiles = t;
  }
}

__global__ __launch_bounds__(256) void scatter_kernel(const int* __restrict__ tok_e,
    const float* __restrict__ tok_w, const int* __restrict__ offs, int* __restrict__ fill,
    int* __restrict__ pair_token, float* __restrict__ pair_w, int* __restrict__ tok_pi){
  int t = blockIdx.x*256 + threadIdx.x;
  if (t >= S_LEN) return;
  #pragma unroll
  for (int sl = 0; sl < 2; sl++){
    int e = tok_e[t*2+sl];
    int pos = atomicAdd(&fill[e], 1);
    int pi = offs[e] + pos;
    pair_token[pi] = t;
    pair_w[pi] = tok_w[t*2+sl];
    tok_pi[t*2+sl] = pi;
  }
}

// ---------------- combine: moe[t] = w0*P[p0] + w1*P[p1] -> bf16 ----------------
__global__ __launch_bounds__(256) void combine_kernel(const float* __restrict__ Pbuf,
    const int* __restrict__ tok_pi, const float* __restrict__ tok_w,
    unsigned short* __restrict__ moe_bf){
  int t = blockIdx.x;
  int d = threadIdx.x;
  float w0 = tok_w[t*2], w1 = tok_w[t*2+1];
  long p0 = (long)tok_pi[t*2]   * DMODEL;
  long p1 = (long)tok_pi[t*2+1] * DMODEL;
  unsigned short* orow = moe_bf + (long)t*DMODEL;
  #pragma unroll
  for (int j = 0; j < 3; j++){
    int dd = d + j*256;
    orow[dd] = f2bf(w0*Pbuf[p0+dd] + w1*Pbuf[p1+dd]);
  }
}

// ---------------- host launch ----------------
extern "C" void kernel_launch(void* const* d_in, const int* in_sizes, int n_in,
                              void* d_out, int out_size, void* d_ws, size_t ws_size,
                              hipStream_t stream){
  (void)in_sizes; (void)n_in; (void)out_size; (void)ws_size;
  const float* hidden = (const float*)d_in[0];
  const float* Wq  = (const float*)d_in[1];
  const float* bq  = (const float*)d_in[2];
  const float* Wk  = (const float*)d_in[3];
  const float* bk  = (const float*)d_in[4];
  const float* Wv  = (const float*)d_in[5];
  const float* bv  = (const float*)d_in[6];
  const float* Wo  = (const float*)d_in[7];
  const float* bo  = (const float*)d_in[8];
  const float* ln1g = (const float*)d_in[9];
  const float* ln1b = (const float*)d_in[10];
  const float* gateW = (const float*)d_in[11];
  const float* gateB = (const float*)d_in[12];
  const float* W1e = (const float*)d_in[13];
  const float* b1e = (const float*)d_in[14];
  const float* W2e = (const float*)d_in[15];
  const float* b2e = (const float*)d_in[16];
  const float* Wd  = (const float*)d_in[17];
  const float* bd  = (const float*)d_in[18];
  const float* ln2g = (const float*)d_in[19];
  const float* ln2b = (const float*)d_in[20];

  float* outL = (float*)d_out;
  float* outG = outL + (size_t)S_LEN*DMODEL;

  const size_t SD = (size_t)S_LEN*DMODEL;
  char* base = (char*)d_ws;
  size_t off = 0;
  auto alloc = [&](size_t bytes)->void*{
    void* r = base + off;
    off = (off + bytes + 255) & ~(size_t)255;
    return r;
  };
  unsigned short* x_hi    = (unsigned short*)alloc(SD*2);
  unsigned short* x_lo    = (unsigned short*)alloc(SD*2);
  unsigned short* wqkv_hi = (unsigned short*)alloc((size_t)2304*768*2);
  unsigned short* wqkv_lo = (unsigned short*)alloc((size_t)2304*768*2);
  unsigned short* wo_hi   = (unsigned short*)alloc((size_t)768*768*2);
  unsigned short* wo_lo   = (unsigned short*)alloc((size_t)768*768*2);
  unsigned short* wd_bf   = (unsigned short*)alloc((size_t)768*768*2);
  unsigned short* w1_bf   = (unsigned short*)alloc((size_t)NEXP*FDIM*DMODEL*2);
  unsigned short* w2_bf   = (unsigned short*)alloc((size_t)NEXP*FDIM*DMODEL*2);
  unsigned short* q_hi  = (unsigned short*)alloc(SD*2);
  unsigned short* q_lo  = (unsigned short*)alloc(SD*2);
  unsigned short* k_hi  = (unsigned short*)alloc(SD*2);
  unsigned short* k_lo  = (unsigned short*)alloc(SD*2);
  unsigned short* vt_hi = (unsigned short*)alloc(SD*2);
  unsigned short* vt_lo = (unsigned short*)alloc(SD*2);
  unsigned short* attn_hi = (unsigned short*)alloc(SD*2);
  unsigned short* attn_lo = (unsigned short*)alloc(SD*2);
  float* preLN1    = (float*)alloc(SD*4);
  float* attnout_f = (float*)alloc(SD*4);
  unsigned short* attnout_bf = (unsigned short*)alloc(SD*2);
  int*   tok_e = (int*)alloc(2*S_LEN*4);
  float* tok_w = (float*)alloc(2*S_LEN*4);
  int*   tok_pi = (int*)alloc(2*S_LEN*4);
  int*   cnt   = (int*)alloc(32*4);      // cnt[0:8], fill at +8
  int*   fill  = cnt + 8;
  int*   offs  = (int*)alloc(32*4);
  int*   tile_e = (int*)alloc(MAXTILES*4);
  int*   tile_m = (int*)alloc(MAXTILES*4);
  int*   ntiles = (int*)alloc(4);
  int*   pair_token = (int*)alloc(NPAIR*4);
  float* pair_w     = (float*)alloc(NPAIR*4);
  unsigned short* Hbuf = (unsigned short*)alloc((size_t)NPAIR*FDIM*2);
  // aliases: q/k/vt planes (6*SD*2 = 37.7MB contiguous) dead after attn_mfma.
  float* Pbuf = (float*)q_hi;
  unsigned short* moe_bf = (unsigned short*)((char*)q_hi + (size_t)NPAIR*DMODEL*4);
  float* preLN2 = preLN1;

  // 1. split hidden -> bf16 hi/lo
  split_kernel<<<dim3((unsigned)(SD/256)), dim3(256), 0, stream>>>(hidden, x_hi, x_lo, (int)SD);
  // 2. weight transposes/converts
  transp_kernel<1><<<dim3(24,24,1), dim3(32,8), 0, stream>>>(Wq, wqkv_hi,           wqkv_lo,           DMODEL, DMODEL, 0, 0);
  transp_kernel<1><<<dim3(24,24,1), dim3(32,8), 0, stream>>>(Wk, wqkv_hi+768*768,   wqkv_lo+768*768,   DMODEL, DMODEL, 0, 0);
  transp_kernel<1><<<dim3(24,24,1), dim3(32,8), 0, stream>>>(Wv, wqkv_hi+2*768*768, wqkv_lo+2*768*768, DMODEL, DMODEL, 0, 0);
  transp_kernel<1><<<dim3(24,24,1), dim3(32,8), 0, stream>>>(Wo, wo_hi, wo_lo, DMODEL, DMODEL, 0, 0);
  transp_kernel<0><<<dim3(24,24,1), dim3(32,8), 0, stream>>>(Wd, wd_bf, nullptr, DMODEL, DMODEL, 0, 0);
  transp_kernel<0><<<dim3(96,24,NEXP), dim3(32,8), 0, stream>>>(W1e, w1_bf, nullptr, DMODEL, FDIM, (long)DMODEL*FDIM, (long)DMODEL*FDIM);
  transp_kernel<0><<<dim3(24,96,NEXP), dim3(32,8), 0, stream>>>(W2e, w2_bf, nullptr, FDIM, DMODEL, (long)DMODEL*FDIM, (long)DMODEL*FDIM);

  // 3. QKV projection -> Q,K hi/lo [h][s][64]; V hi/lo transposed [h][d][s]
  GemmP pq = {};
  pq.A = x_hi; pq.Alo = x_lo; pq.B = wqkv_hi; pq.Blo = wqkv_lo;
  pq.M = S_LEN; pq.N = 2304; pq.K = DMODEL;
  pq.bias = bq; pq.bias2 = bk; pq.bias3 = bv;
  pq.qhi = q_hi; pq.qlo = q_lo; pq.khi = k_hi; pq.klo = k_lo; pq.vthi = vt_hi; pq.vtlo = vt_lo;
  gemm_bt<0,2><<<dim3(18,32,1), dim3(256), 0, stream>>>(pq);

  // 4. MFMA attention -> attn hi/lo bf16 planes
  attn_mfma<<<dim3(16,NHEADS,4), dim3(256), 0, stream>>>(q_hi, q_lo, k_hi, k_lo, vt_hi, vt_lo, attn_hi, attn_lo);

  // 5. Wo projection + bias + residual -> preLN1 (fp32)
  GemmP pw = {};
  pw.A = attn_hi; pw.Alo = attn_lo; pw.B = wo_hi; pw.Blo = wo_lo;
  pw.M = S_LEN; pw.N = DMODEL; pw.K = DMODEL;
  pw.bias = bo; pw.resid = hidden; pw.outF = preLN1;
  gemm_bt<1,2><<<dim3(6,32,1), dim3(256), 0, stream>>>(pw);

  // 6. LN1 -> attnout (fp32 + bf16)
  ln_kernel<<<dim3(S_LEN), dim3(256), 0, stream>>>(preLN1, ln1g, ln1b, attnout_f, attnout_bf);

  // 7. zero routing counters
  hipMemsetAsync(cnt, 0, 64, stream);

  // 8. gate + routing (+ compacted tile list)
  gate_kernel<<<dim3(S_LEN), dim3(64), 0, stream>>>(attnout_f, gateW, gateB, outG, tok_e, tok_w, cnt);
  scan_kernel<<<dim3(1), dim3(64), 0, stream>>>(cnt, offs, tile_e, tile_m, ntiles);
  scatter_kernel<<<dim3(S_LEN/256), dim3(256), 0, stream>>>(tok_e, tok_w, offs, fill, pair_token, pair_w, tok_pi);

  // 9. MoE expert GEMMs (top-2 sparse), 256M x 128N shared-stage blocks, compacted tiles
  GemmP p1 = {};
  p1.A = attnout_bf; p1.B = w1_bf; p1.M = S_LEN; p1.N = FDIM; p1.K = DMODEL;
  p1.bias = b1e; p1.outBF = Hbuf;
  p1.pair_token = pair_token; p1.cnt = cnt; p1.offs = offs;
  p1.tile_e = tile_e; p1.tile_m = tile_m; p1.ntiles = ntiles;
  gemm_big<2><<<dim3(24,MAXTILES), dim3(512), 0, stream>>>(p1);

  GemmP p2 = {};
  p2.A = Hbuf; p2.B = w2_bf; p2.M = S_LEN; p2.N = DMODEL; p2.K = FDIM;
  p2.bias = b2e; p2.outF = Pbuf;
  p2.pair_token = pair_token; p2.pair_w = pair_w; p2.cnt = cnt; p2.offs = offs;
  p2.tile_e = tile_e; p2.tile_m = tile_m; p2.ntiles = ntiles;
  gemm_big<3><<<dim3(6,MAXTILES), dim3(512), 0, stream>>>(p2);

  // 10. combine pairs -> moe bf16; Wd + bias + residual(attention_output) -> preLN2
  combine_kernel<<<dim3(S_LEN), dim3(256), 0, stream>>>(Pbuf, tok_pi, tok_w, moe_bf);
  GemmP pd = {};
  pd.A = moe_bf; pd.B = wd_bf; pd.M = S_LEN; pd.N = DMODEL; pd.K = DMODEL;
  pd.bias = bd; pd.resid = attnout_f; pd.outF = preLN2;
  gemm_bt<4,1><<<dim3(6,32,1), dim3(256), 0, stream>>>(pd);

  // 11. LN2 -> layer_output
  ln_kernel<<<dim3(S_LEN), dim3(256), 0, stream>>>(preLN2, ln2g, ln2b, outL, nullptr);
}

// Round 2
// 729.701 us; speedup vs baseline: 1.1555x; 1.1555x over previous
//
#include <hip/hip_runtime.h>
#include <math.h>

#define S_LEN 4096
#define DMODEL 768
#define NHEADS 12
#define DH 64
#define FDIM 3072
#define NEXP 7
#define NPAIR (2*S_LEN)
#define MAXTILES 40

typedef _Float16 f16x8 __attribute__((ext_vector_type(8)));
typedef float f32x4 __attribute__((ext_vector_type(4)));

__device__ __forceinline__ unsigned short f2h(float f){
  union { _Float16 h; unsigned short u; } v; v.h = (_Float16)f; return v.u;
}
__device__ __forceinline__ float gelu_f(float x){
  return 0.5f * x * (1.0f + erff(x * 0.7071067811865475f));
}
__device__ __forceinline__ f32x4 mfma16(f16x8 a, f16x8 b, f32x4 c){
  return __builtin_amdgcn_mfma_f32_16x16x32_f16(a, b, c, 0, 0, 0);
}
// async global->LDS, 16 B per lane. LDS side must be wave-uniform base + lane*16.
__device__ __forceinline__ void glds16(const void* g, void* l){
  __builtin_amdgcn_global_load_lds((const __attribute__((address_space(1))) unsigned*)g,
                                   (__attribute__((address_space(3))) unsigned*)l, 16, 0, 0);
}

// ---------------- elementwise fp32 -> fp16 ----------------
__global__ __launch_bounds__(256) void split_kernel(const float* __restrict__ in,
    unsigned short* __restrict__ out, int n){
  int i = blockIdx.x*256 + threadIdx.x;
  if (i >= n) return;
  out[i] = f2h(in[i]);
}

// ---------------- tiled transpose + convert: in [mat][R][C] f32 -> out [mat][C][R] fp16 ----------------
__global__ __launch_bounds__(256) void transp_kernel(const float* __restrict__ in,
    unsigned short* __restrict__ out,
    int R, int C, long inStride, long outStride){
  const float* ip = in + (long)blockIdx.z * inStride;
  long ob = (long)blockIdx.z * outStride;
  __shared__ float tile[32][33];
  int c0 = blockIdx.x*32, r0 = blockIdx.y*32;
  int tx = threadIdx.x, ty = threadIdx.y;
  for (int i = ty; i < 32; i += 8)
    tile[i][tx] = ip[(long)(r0+i)*C + c0 + tx];
  __syncthreads();
  int t  = tx + ty*32;
  int sx = t & 15;        // r-pair index
  int sc = t >> 4;        // col group
  #pragma unroll
  for (int j = 0; j < 2; j++){
    int cc = sc + j*16;
    float v0 = tile[sx*2][cc], v1 = tile[sx*2+1][cc];
    long oidx = ob + (long)(c0+cc)*R + r0 + sx*2;
    unsigned uh = (unsigned)f2h(v0) | ((unsigned)f2h(v1) << 16);
    *(unsigned*)(out + oidx) = uh;
  }
}

// ---------------- generic 128x128x32 fp16 MFMA GEMM, B^T ("Bt[n][k]") layout ----------------
// MODE: 0=QKV  1=WO  4=WD
struct GemmP {
  const unsigned short* A;
  const unsigned short* B;
  int M, N, K;
  const float* bias;  const float* bias2; const float* bias3;
  const float* resid;
  float* outF;
  unsigned short* outBF;
  unsigned short *qh,*kh,*vth;
  const int* pair_token;
  const float* pair_w;
  const int* cnt;
  const int* offs;
  const int* tile_e;
  const int* tile_m;
  const int* ntiles;
};

template<int MODE>
__global__ __launch_bounds__(256, 2) void gemm_bt(GemmP p){
  const int tid  = threadIdx.x;
  const int lane = tid & 63;
  const int wave = tid >> 6;
  const int quad = lane >> 4;
  const int ln   = lane & 15;
  const int wr = wave >> 1, wc = wave & 1;
  const int bn0 = blockIdx.x * 128;
  const int bm0 = blockIdx.y * 128;
  const int K = p.K;

  long aoff[2]; long boff[2]; int koff[2];
  #pragma unroll
  for (int j = 0; j < 2; j++){
    int c = tid + j*256;
    int row = c >> 2;
    koff[j] = (c & 3) * 8;
    aoff[j] = (long)(bm0 + row) * K;
    boff[j] = (long)(bn0 + row) * K;
  }

  // double-buffered stages: issue next-tile loads before compute (latency hides under MFMA)
  __shared__ __align__(16) unsigned short As[2][128*32];
  __shared__ __align__(16) unsigned short Bs[2][128*32];

  auto stage = [&](int k0, int buf){
    #pragma unroll
    for (int j = 0; j < 2; j++){
      int c = tid + j*256;
      glds16(p.A + aoff[j] + k0 + koff[j], &As[buf][c*8]);
      glds16(p.B + boff[j] + k0 + koff[j], &Bs[buf][c*8]);
    }
  };

  f32x4 zero4 = {0.f, 0.f, 0.f, 0.f};
  f32x4 acc[4][4];
  #pragma unroll
  for (int i = 0; i < 4; i++)
    #pragma unroll
    for (int j = 0; j < 4; j++) acc[i][j] = zero4;

  stage(0, 0);
  __syncthreads();          // drains vmcnt(0): tile 0 resident
  int cur = 0;

  for (int k0 = 0; k0 < K; k0 += 32){
    if (k0 + 32 < K) stage(k0 + 32, cur ^ 1);
    f16x8 af[4], bfr[4];
    #pragma unroll
    for (int mt = 0; mt < 4; mt++)
      af[mt] = *(const f16x8*)&As[cur][(wr*64 + mt*16 + ln)*32 + quad*8];
    #pragma unroll
    for (int nt = 0; nt < 4; nt++)
      bfr[nt] = *(const f16x8*)&Bs[cur][(wc*64 + nt*16 + ln)*32 + quad*8];
    #pragma unroll
    for (int mt = 0; mt < 4; mt++)
      #pragma unroll
      for (int nt = 0; nt < 4; nt++)
        acc[mt][nt] = mfma16(af[mt], bfr[nt], acc[mt][nt]);
    __syncthreads();        // next tile landed; protects buffer reuse
    cur ^= 1;
  }

  #pragma unroll
  for (int mt = 0; mt < 4; mt++){
    #pragma unroll
    for (int nt = 0; nt < 4; nt++){
      #pragma unroll
      for (int r = 0; r < 4; r++){
        int gm = bm0 + wr*64 + mt*16 + quad*4 + r;
        int gn = bn0 + wc*64 + nt*16 + ln;
        float v = acc[mt][nt][r];
        if (MODE == 0){
          int which = gn >= 1536 ? 2 : (gn >= 768 ? 1 : 0);
          int nn = gn - which*768;
          int hh = nn >> 6, dh = nn & 63;
          if (which == 0){
            float q = (v + p.bias[nn]) * 0.125f;
            long o = ((long)hh*S_LEN + gm)*64 + dh;
            p.qh[o] = f2h(q);
          } else if (which == 1){
            float kv = v + p.bias2[nn];
            long o = ((long)hh*S_LEN + gm)*64 + dh;
            p.kh[o] = f2h(kv);
          } else {
            float vv = v + p.bias3[nn];
            long o = ((long)hh*64 + dh)*S_LEN + gm;   // V^T: [h][d][s]
            p.vth[o] = f2h(vv);
          }
        } else if (MODE == 1 || MODE == 4){
          long i = (long)gm*DMODEL + gn;
          p.outF[i] = v + p.bias[gn] + p.resid[i];
        }
      }
    }
  }
}

// ---------------- 256M x 128N MoE GEMM, 512 threads / 8 waves ----------------
// Compacted tile list (blockIdx.y -> (expert, m0)) + double-buffered prefetch pipeline.
// MODE: 2=MOE1(gather A by pair_token)  3=MOE2(contiguous pair rows)
template<int MODE>
__global__ __launch_bounds__(512, 4) void gemm_big(GemmP p){
  const int ty = blockIdx.y;
  if (ty >= *p.ntiles) return;
  const int e   = p.tile_e[ty];
  const int bm0 = p.tile_m[ty];

  const int tid  = threadIdx.x;
  const int lane = tid & 63;
  const int wave = tid >> 6;          // 0..7, 4x2 (wr x wc)
  const int quad = lane >> 4;
  const int ln   = lane & 15;
  const int wr = wave >> 1, wc = wave & 1;
  const int bn0 = blockIdx.x * 128;
  const int K = p.K;

  const int eoff = p.offs[e];
  const int Mloc = p.cnt[e];
  const unsigned short* Bp = p.B + (long)e * FDIM * DMODEL;

  long aoff[2]; int koffA[2];
  #pragma unroll
  for (int j = 0; j < 2; j++){
    int c = tid + j*512;
    int row = c >> 2;
    koffA[j] = (c & 3) * 8;
    int r = bm0 + row; if (r >= Mloc) r = Mloc - 1;
    aoff[j] = (MODE == 2) ? (long)p.pair_token[eoff + r] * K : (long)(eoff + r) * K;
  }
  long boff; int koffB;
  {
    int row = tid >> 2;
    koffB = (tid & 3) * 8;
    boff = (long)(bn0 + row) * K;
  }

  __shared__ __align__(16) unsigned short As[2][256*32];
  __shared__ __align__(16) unsigned short Bs[2][128*32];

  auto stage = [&](int k0, int buf){
    #pragma unroll
    for (int j = 0; j < 2; j++){
      int c = tid + j*512;
      glds16(p.A + aoff[j] + k0 + koffA[j], &As[buf][c*8]);
    }
    glds16(Bp + boff + k0 + koffB, &Bs[buf][tid*8]);
  };

  f32x4 zero4 = {0.f, 0.f, 0.f, 0.f};
  f32x4 acc[4][4];
  #pragma unroll
  for (int i = 0; i < 4; i++)
    #pragma unroll
    for (int j = 0; j < 4; j++) acc[i][j] = zero4;

  stage(0, 0);
  __syncthreads();
  int cur = 0;

  for (int k0 = 0; k0 < K; k0 += 32){
    if (k0 + 32 < K) stage(k0 + 32, cur ^ 1);
    f16x8 af[4], bfr[4];
    #pragma unroll
    for (int mt = 0; mt < 4; mt++)
      af[mt] = *(const f16x8*)&As[cur][(wr*64 + mt*16 + ln)*32 + quad*8];
    #pragma unroll
    for (int nt = 0; nt < 4; nt++)
      bfr[nt] = *(const f16x8*)&Bs[cur][(wc*64 + nt*16 + ln)*32 + quad*8];
    #pragma unroll
    for (int mt = 0; mt < 4; mt++)
      #pragma unroll
      for (int nt = 0; nt < 4; nt++)
        acc[mt][nt] = mfma16(af[mt], bfr[nt], acc[mt][nt]);
    __syncthreads();
    cur ^= 1;
  }

  #pragma unroll
  for (int mt = 0; mt < 4; mt++){
    #pragma unroll
    for (int nt = 0; nt < 4; nt++){
      #pragma unroll
      for (int r = 0; r < 4; r++){
        int gm = bm0 + wr*64 + mt*16 + quad*4 + r;
        int gn = bn0 + wc*64 + nt*16 + ln;
        if (gm < Mloc){
          float v = acc[mt][nt][r];
          if (MODE == 2){
            v = gelu_f(v + p.bias[(long)e*FDIM + gn]);
            p.outBF[(long)(eoff + gm)*FDIM + gn] = f2h(v);
          } else {
            int pi = eoff + gm;
            p.outF[(long)pi*DMODEL + gn] = v + p.bias[(long)e*DMODEL + gn];
          }
        }
      }
    }
  }
}

// ---------------- MFMA sliding-window attention, fp16 single-plane ----------------
// grid (16 chunks, 12 heads, 4 strips of 64 q); block 256 (4 waves x 16-q sub-strip)
__global__ __launch_bounds__(256) void attn_mfma(
    const unsigned short* __restrict__ Qh,
    const unsigned short* __restrict__ Kh,
    const unsigned short* __restrict__ Vth,
    unsigned short* __restrict__ attn_h){
  const int c = blockIdx.x, h = blockIdx.y, qb = blockIdx.z;
  const int tid = threadIdx.x;
  const int lane = tid & 63, w = tid >> 6;
  const int quad = lane >> 4, ln = lane & 15;
  const int q0 = c*256 + qb*64;
  const int qw = q0 + w*16;

  __shared__ __align__(16) unsigned short Ks[64*64];
  __shared__ __align__(16) unsigned short Vs[64*64];
  __shared__ __align__(16) unsigned short Ps[4][16*72];

  f16x8 qf[2];
  {
    long qrow = ((long)h*S_LEN + qw + ln)*64 + quad*8;
    qf[0] = *(const f16x8*)(Qh + qrow);
    qf[1] = *(const f16x8*)(Qh + qrow + 32);
  }

  float m_s[4], l_s[4];
  f32x4 Oc[4];
  f32x4 z4 = {0.f,0.f,0.f,0.f};
  #pragma unroll
  for (int r = 0; r < 4; r++){ m_s[r] = -1e30f; l_s[r] = 0.f; }
  #pragma unroll
  for (int nt = 0; nt < 4; nt++) Oc[nt] = z4;

  const unsigned short* KB = Kh + (long)h*S_LEN*64;
  const unsigned short* VB = Vth + (long)h*64*S_LEN;

  for (int kb = 0; kb < 12; kb++){
    const int kstart = c*256 - 256 + kb*64;
    if (kstart + 63 < 0 || kstart >= S_LEN) continue;
    if (kstart + 63 < q0 - 256 || kstart > q0 + 63 + 256) continue;
    __syncthreads();
    #pragma unroll
    for (int p2 = 0; p2 < 2; p2++){
      int idx = p2*256 + tid;
      int row = idx >> 3;
      int pc  = idx & 7;
      int lc  = pc ^ (row & 7);
      int ka = kstart + row;
      int kac = ka < 0 ? 0 : (ka > S_LEN-1 ? S_LEN-1 : ka);
      long gK = (long)kac*64 + lc*8;
      glds16(KB + gK, &Ks[idx*8]);
      int ks0 = kstart + lc*8;
      ks0 = ks0 < 0 ? 0 : (ks0 > S_LEN-8 ? S_LEN-8 : ks0);
      long gV = (long)row*S_LEN + ks0;
      glds16(VB + gV, &Vs[idx*8]);
    }
    __syncthreads();
    if (kstart + 63 < qw - 256 || kstart > qw + 15 + 256) continue;

    f32x4 Sc[4];
    #pragma unroll
    for (int nt = 0; nt < 4; nt++) Sc[nt] = z4;
    #pragma unroll
    for (int kc = 0; kc < 2; kc++){
      f16x8 bh[4];
      #pragma unroll
      for (int nt = 0; nt < 4; nt++){
        int row = nt*16 + ln;
        int o = row*64 + (((kc*4 + quad) ^ (row & 7))*8);
        bh[nt] = *(const f16x8*)&Ks[o];
      }
      #pragma unroll
      for (int nt = 0; nt < 4; nt++)
        Sc[nt] = mfma16(qf[kc], bh[nt], Sc[nt]);
    }
    bool interior = (kstart >= qw - 241) && (kstart <= qw + 193) &&
                    (kstart >= 0) && (kstart + 63 <= S_LEN - 1);
    if (!interior){
      #pragma unroll
      for (int nt = 0; nt < 4; nt++){
        int ka = kstart + nt*16 + ln;
        #pragma unroll
        for (int r = 0; r < 4; r++){
          int qa = qw + quad*4 + r;
          bool v = (ka >= 0) && (ka < S_LEN) && (ka >= qa - 256) && (ka <= qa + 256);
          if (!v) Sc[nt][r] = -3.0e38f;
        }
      }
    }
    float bm[4];
    #pragma unroll
    for (int r = 0; r < 4; r++)
      bm[r] = fmaxf(fmaxf(Sc[0][r], Sc[1][r]), fmaxf(Sc[2][r], Sc[3][r]));
    #pragma unroll
    for (int off = 1; off < 16; off <<= 1)
      #pragma unroll
      for (int r = 0; r < 4; r++) bm[r] = fmaxf(bm[r], __shfl_xor(bm[r], off));
    float al[4];
    #pragma unroll
    for (int r = 0; r < 4; r++){
      float mnew = fmaxf(m_s[r], bm[r]);
      al[r] = __expf(m_s[r] - mnew);
      m_s[r] = mnew;
    }
    float psum[4] = {0.f,0.f,0.f,0.f};
    #pragma unroll
    for (int nt = 0; nt < 4; nt++){
      #pragma unroll
      for (int r = 0; r < 4; r++){
        float pv = __expf(Sc[nt][r] - m_s[r]);
        psum[r] += pv;
        int o = (quad*4 + r)*72 + nt*16 + ln;
        Ps[w][o] = f2h(pv);
      }
    }
    #pragma unroll
    for (int off = 1; off < 16; off <<= 1)
      #pragma unroll
      for (int r = 0; r < 4; r++) psum[r] += __shfl_xor(psum[r], off);
    #pragma unroll
    for (int r = 0; r < 4; r++) l_s[r] = l_s[r]*al[r] + psum[r];
    #pragma unroll
    for (int nt = 0; nt < 4; nt++)
      #pragma unroll
      for (int r = 0; r < 4; r++) Oc[nt][r] *= al[r];
    asm volatile("s_waitcnt lgkmcnt(0)" ::: "memory");
    #pragma unroll
    for (int kc = 0; kc < 2; kc++){
      f16x8 ph = *(const f16x8*)&Ps[w][ln*72 + kc*32 + quad*8];
      #pragma unroll
      for (int nt = 0; nt < 4; nt++){
        int row = nt*16 + ln;
        int o = row*64 + (((kc*4 + quad) ^ (row & 7))*8);
        f16x8 vh = *(const f16x8*)&Vs[o];
        Oc[nt] = mfma16(ph, vh, Oc[nt]);
      }
    }
  }
  float inv[4];
  #pragma unroll
  for (int r = 0; r < 4; r++) inv[r] = 1.f / l_s[r];
  #pragma unroll
  for (int nt = 0; nt < 4; nt++){
    #pragma unroll
    for (int r = 0; r < 4; r++){
      int qa = qw + quad*4 + r;
      long o = (long)qa*DMODEL + h*64 + nt*16 + ln;
      attn_h[o] = f2h(Oc[nt][r] * inv[r]);
    }
  }
}

// ---------------- LayerNorm (fp32), optional fp16 copy ----------------
__global__ __launch_bounds__(256) void ln_kernel(const float* __restrict__ x,
    const float* __restrict__ g, const float* __restrict__ b,
    float* __restrict__ outF, unsigned short* __restrict__ outH){
  int s = blockIdx.x;
  const float* row = x + (long)s*DMODEL;
  int t = threadIdx.x;
  float v0 = row[t], v1 = row[t+256], v2 = row[t+512];
  float sum = v0+v1+v2;
  float sq  = v0*v0 + v1*v1 + v2*v2;
  for (int o = 32; o > 0; o >>= 1){ sum += __shfl_xor(sum, o); sq += __shfl_xor(sq, o); }
  __shared__ float s1[4], s2[4];
  int wv = t >> 6;
  if ((t & 63) == 0){ s1[wv] = sum; s2[wv] = sq; }
  __syncthreads();
  sum = s1[0]+s1[1]+s1[2]+s1[3];
  sq  = s2[0]+s2[1]+s2[2]+s2[3];
  float mean = sum * (1.0f/DMODEL);
  float var  = sq  * (1.0f/DMODEL) - mean*mean;
  float inv = rsqrtf(var + 1e-5f);
  float* orow = outF + (long)s*DMODEL;
  unsigned short* hrow = outH ? outH + (long)s*DMODEL : (unsigned short*)0;
  #pragma unroll
  for (int j = 0; j < 3; j++){
    int d = t + j*256;
    float y = (row[d] - mean) * inv * g[d] + b[d];
    orow[d] = y;
    if (hrow) hrow[d] = f2h(y);
  }
}

// ---------------- gate: fp32 logits, top-2, softmax, routing records ----------------
__global__ __launch_bounds__(64) void gate_kernel(const float* __restrict__ x,
    const float* __restrict__ gw, const float* __restrict__ gb,
    float* __restrict__ gate_out, int* __restrict__ tok_e,
    float* __restrict__ tok_w, int* __restrict__ cnt){
  int s = blockIdx.x;
  int lane = threadIdx.x;
  float acc[NEXP];
  #pragma unroll
  for (int e = 0; e < NEXP; e++) acc[e] = 0.f;
  const float* xr = x + (long)s*DMODEL;
  for (int d = lane; d < DMODEL; d += 64){
    float xv = xr[d];
    const float* wr = gw + (long)d*NEXP;
    #pragma unroll
    for (int e = 0; e < NEXP; e++) acc[e] += xv * wr[e];
  }
  #pragma unroll
  for (int e = 0; e < NEXP; e++){
    float v = acc[e];
    for (int o = 32; o > 0; o >>= 1) v += __shfl_xor(v, o);
    acc[e] = v;
  }
  if (lane == 0){
    #pragma unroll
    for (int e = 0; e < NEXP; e++) acc[e] += gb[e];
    int i0 = 0;
    for (int e = 1; e < NEXP; e++) if (acc[e] > acc[i0]) i0 = e;
    int i1 = -1;
    for (int e = 0; e < NEXP; e++) if (e != i0 && (i1 < 0 || acc[e] > acc[i1])) i1 = e;
    float e1 = expf(acc[i1] - acc[i0]);
    float inv = 1.f / (1.f + e1);
    float w0 = inv, w1 = e1 * inv;
    float* go = gate_out + (long)s*NEXP;
    #pragma unroll
    for (int e = 0; e < NEXP; e++) go[e] = 0.f;
    go[i0] = w0; go[i1] = w1;
    tok_e[s*2] = i0; tok_e[s*2+1] = i1;
    tok_w[s*2] = w0; tok_w[s*2+1] = w1;
    atomicAdd(&cnt[i0], 1);
    atomicAdd(&cnt[i1], 1);
  }
}

// scan + compacted tile list: tiles = (expert, m0) pairs with m0 < cnt[e], step 256
__global__ void scan_kernel(const int* __restrict__ cnt, int* __restrict__ offs,
                            int* __restrict__ tile_e, int* __restrict__ tile_m,
                            int* __restrict__ ntiles){
  if (threadIdx.x == 0 && blockIdx.x == 0){
    int s = 0, t = 0;
    for (int e = 0; e < NEXP; e++){
      offs[e] = s;
      for (int m0 = 0; m0 < cnt[e]; m0 += 256){
        tile_e[t] = e; tile_m[t] = m0; t++;
      }
      s += cnt[e];
    }
    *ntiles = t;
  }
}

__global__ __launch_bounds__(256) void scatter_kernel(const int* __restrict__ tok_e,
    const float* __restrict__ tok_w, const int* __restrict__ offs, int* __restrict__ fill,
    int* __restrict__ pair_token, float* __restrict__ pair_w, int* __restrict__ tok_pi){
  int t = blockIdx.x*256 + threadIdx.x;
  if (t >= S_LEN) return;
  #pragma unroll
  for (int sl = 0; sl < 2; sl++){
    int e = tok_e[t*2+sl];
    int pos = atomicAdd(&fill[e], 1);
    int pi = offs[e] + pos;
    pair_token[pi] = t;
    pair_w[pi] = tok_w[t*2+sl];
    tok_pi[t*2+sl] = pi;
  }
}

// ---------------- combine: moe[t] = w0*P[p0] + w1*P[p1] -> fp16 ----------------
__global__ __launch_bounds__(256) void combine_kernel(const float* __restrict__ Pbuf,
    const int* __restrict__ tok_pi, const float* __restrict__ tok_w,
    unsigned short* __restrict__ moe_h){
  int t = blockIdx.x;
  int d = threadIdx.x;
  float w0 = tok_w[t*2], w1 = tok_w[t*2+1];
  long p0 = (long)tok_pi[t*2]   * DMODEL;
  long p1 = (long)tok_pi[t*2+1] * DMODEL;
  unsigned short* orow = moe_h + (long)t*DMODEL;
  #pragma unroll
  for (int j = 0; j < 3; j++){
    int dd = d + j*256;
    orow[dd] = f2h(w0*Pbuf[p0+dd] + w1*Pbuf[p1+dd]);
  }
}

// ---------------- host launch ----------------
extern "C" void kernel_launch(void* const* d_in, const int* in_sizes, int n_in,
                              void* d_out, int out_size, void* d_ws, size_t ws_size,
                              hipStream_t stream){
  (void)in_sizes; (void)n_in; (void)out_size; (void)ws_size;
  const float* hidden = (const float*)d_in[0];
  const float* Wq  = (const float*)d_in[1];
  const float* bq  = (const float*)d_in[2];
  const float* Wk  = (const float*)d_in[3];
  const float* bk  = (const float*)d_in[4];
  const float* Wv  = (const float*)d_in[5];
  const float* bv  = (const float*)d_in[6];
  const float* Wo  = (const float*)d_in[7];
  const float* bo  = (const float*)d_in[8];
  const float* ln1g = (const float*)d_in[9];
  const float* ln1b = (const float*)d_in[10];
  const float* gateW = (const float*)d_in[11];
  const float* gateB = (const float*)d_in[12];
  const float* W1e = (const float*)d_in[13];
  const float* b1e = (const float*)d_in[14];
  const float* W2e = (const float*)d_in[15];
  const float* b2e = (const float*)d_in[16];
  const float* Wd  = (const float*)d_in[17];
  const float* bd  = (const float*)d_in[18];
  const float* ln2g = (const float*)d_in[19];
  const float* ln2b = (const float*)d_in[20];

  float* outL = (float*)d_out;
  float* outG = outL + (size_t)S_LEN*DMODEL;

  const size_t SD = (size_t)S_LEN*DMODEL;
  char* base = (char*)d_ws;
  size_t off = 0;
  auto alloc = [&](size_t bytes)->void*{
    void* r = base + off;
    off = (off + bytes + 255) & ~(size_t)255;
    return r;
  };
  unsigned short* x_h     = (unsigned short*)alloc(SD*2);
  unsigned short* wqkv_h  = (unsigned short*)alloc((size_t)2304*768*2);
  unsigned short* wo_h    = (unsigned short*)alloc((size_t)768*768*2);
  unsigned short* wd_h    = (unsigned short*)alloc((size_t)768*768*2);
  unsigned short* w1_h    = (unsigned short*)alloc((size_t)NEXP*FDIM*DMODEL*2);
  unsigned short* w2_h    = (unsigned short*)alloc((size_t)NEXP*FDIM*DMODEL*2);
  unsigned short* q_h   = (unsigned short*)alloc(SD*2);
  unsigned short* k_h   = (unsigned short*)alloc(SD*2);
  unsigned short* vt_h  = (unsigned short*)alloc(SD*2);
  unsigned short* attn_h = (unsigned short*)alloc(SD*2);
  float* preLN1    = (float*)alloc(SD*4);
  float* attnout_f = (float*)alloc(SD*4);
  unsigned short* attnout_h = (unsigned short*)alloc(SD*2);
  int*   tok_e = (int*)alloc(2*S_LEN*4);
  float* tok_w = (float*)alloc(2*S_LEN*4);
  int*   tok_pi = (int*)alloc(2*S_LEN*4);
  int*   cnt   = (int*)alloc(32*4);      // cnt[0:8], fill at +8
  int*   fill  = cnt + 8;
  int*   offs  = (int*)alloc(32*4);
  int*   tile_e = (int*)alloc(MAXTILES*4);
  int*   tile_m = (int*)alloc(MAXTILES*4);
  int*   ntiles = (int*)alloc(4);
  int*   pair_token = (int*)alloc(NPAIR*4);
  float* pair_w     = (float*)alloc(NPAIR*4);
  unsigned short* Hbuf = (unsigned short*)alloc((size_t)NPAIR*FDIM*2);
  float* Pbuf = (float*)alloc((size_t)NPAIR*DMODEL*4);
  unsigned short* moe_h = (unsigned short*)alloc(SD*2);
  float* preLN2 = preLN1;

  // 1. hidden -> fp16
  split_kernel<<<dim3((unsigned)(SD/256)), dim3(256), 0, stream>>>(hidden, x_h, (int)SD);
  // 2. weight transposes/converts (all single-plane fp16)
  transp_kernel<<<dim3(24,24,1), dim3(32,8), 0, stream>>>(Wq, wqkv_h,           DMODEL, DMODEL, 0, 0);
  transp_kernel<<<dim3(24,24,1), dim3(32,8), 0, stream>>>(Wk, wqkv_h+768*768,   DMODEL, DMODEL, 0, 0);
  transp_kernel<<<dim3(24,24,1), dim3(32,8), 0, stream>>>(Wv, wqkv_h+2*768*768, DMODEL, DMODEL, 0, 0);
  transp_kernel<<<dim3(24,24,1), dim3(32,8), 0, stream>>>(Wo, wo_h, DMODEL, DMODEL, 0, 0);
  transp_kernel<<<dim3(24,24,1), dim3(32,8), 0, stream>>>(Wd, wd_h, DMODEL, DMODEL, 0, 0);
  transp_kernel<<<dim3(96,24,NEXP), dim3(32,8), 0, stream>>>(W1e, w1_h, DMODEL, FDIM, (long)DMODEL*FDIM, (long)DMODEL*FDIM);
  transp_kernel<<<dim3(24,96,NEXP), dim3(32,8), 0, stream>>>(W2e, w2_h, FDIM, DMODEL, (long)DMODEL*FDIM, (long)DMODEL*FDIM);

  // 3. QKV projection -> Q,K [h][s][64]; V transposed [h][d][s]  (fp16)
  GemmP pq = {};
  pq.A = x_h; pq.B = wqkv_h;
  pq.M = S_LEN; pq.N = 2304; pq.K = DMODEL;
  pq.bias = bq; pq.bias2 = bk; pq.bias3 = bv;
  pq.qh = q_h; pq.kh = k_h; pq.vth = vt_h;
  gemm_bt<0><<<dim3(18,32,1), dim3(256), 0, stream>>>(pq);

  // 4. MFMA attention -> attn fp16
  attn_mfma<<<dim3(16,NHEADS,4), dim3(256), 0, stream>>>(q_h, k_h, vt_h, attn_h);

  // 5. Wo projection + bias + residual -> preLN1 (fp32)
  GemmP pw = {};
  pw.A = attn_h; pw.B = wo_h;
  pw.M = S_LEN; pw.N = DMODEL; pw.K = DMODEL;
  pw.bias = bo; pw.resid = hidden; pw.outF = preLN1;
  gemm_bt<1><<<dim3(6,32,1), dim3(256), 0, stream>>>(pw);

  // 6. LN1 -> attnout (fp32 + fp16)
  ln_kernel<<<dim3(S_LEN), dim3(256), 0, stream>>>(preLN1, ln1g, ln1b, attnout_f, attnout_h);

  // 7. zero routing counters
  hipMemsetAsync(cnt, 0, 64, stream);

  // 8. gate + routing (+ compacted tile list)
  gate_kernel<<<dim3(S_LEN), dim3(64), 0, stream>>>(attnout_f, gateW, gateB, outG, tok_e, tok_w, cnt);
  scan_kernel<<<dim3(1), dim3(64), 0, stream>>>(cnt, offs, tile_e, tile_m, ntiles);
  scatter_kernel<<<dim3(S_LEN/256), dim3(256), 0, stream>>>(tok_e, tok_w, offs, fill, pair_token, pair_w, tok_pi);

  // 9. MoE expert GEMMs (top-2 sparse), 256M x 128N shared-stage blocks, compacted tiles
  GemmP p1 = {};
  p1.A = attnout_h; p1.B = w1_h; p1.M = S_LEN; p1.N = FDIM; p1.K = DMODEL;
  p1.bias = b1e; p1.outBF = Hbuf;
  p1.pair_token = pair_token; p1.cnt = cnt; p1.offs = offs;
  p1.tile_e = tile_e; p1.tile_m = tile_m; p1.ntiles = ntiles;
  gemm_big<2><<<dim3(24,MAXTILES), dim3(512), 0, stream>>>(p1);

  GemmP p2 = {};
  p2.A = Hbuf; p2.B = w2_h; p2.M = S_LEN; p2.N = DMODEL; p2.K = FDIM;
  p2.bias = b2e; p2.outF = Pbuf;
  p2.pair_token = pair_token; p2.pair_w = pair_w; p2.cnt = cnt; p2.offs = offs;
  p2.tile_e = tile_e; p2.tile_m = tile_m; p2.ntiles = ntiles;
  gemm_big<3><<<dim3(6,MAXTILES), dim3(512), 0, stream>>>(p2);

  // 10. combine pairs -> moe fp16; Wd + bias + residual(attention_output) -> preLN2
  combine_kernel<<<dim3(S_LEN), dim3(256), 0, stream>>>(Pbuf, tok_pi, tok_w, moe_h);
  GemmP pd = {};
  pd.A = moe_h; pd.B = wd_h; pd.M = S_LEN; pd.N = DMODEL; pd.K = DMODEL;
  pd.bias = bd; pd.resid = attnout_f; pd.outF = preLN2;
  gemm_bt<4><<<dim3(6,32,1), dim3(256), 0, stream>>>(pd);

  // 11. LN2 -> layer_output
  ln_kernel<<<dim3(S_LEN), dim3(256), 0, stream>>>(preLN2, ln2g, ln2b, outL, nullptr);
}

// Round 3
// 609.483 us; speedup vs baseline: 1.3834x; 1.1972x over previous
//
#include <hip/hip_runtime.h>
#include <math.h>

#define S_LEN 4096
#define DMODEL 768
#define NHEADS 12
#define DH 64
#define FDIM 3072
#define NEXP 7
#define NPAIR (2*S_LEN)
#define MAXTILES 40

typedef _Float16 f16x8 __attribute__((ext_vector_type(8)));
typedef float f32x4 __attribute__((ext_vector_type(4)));

__device__ __forceinline__ unsigned short f2h(float f){
  union { _Float16 h; unsigned short u; } v; v.h = (_Float16)f; return v.u;
}
__device__ __forceinline__ float gelu_f(float x){
  return 0.5f * x * (1.0f + erff(x * 0.7071067811865475f));
}
__device__ __forceinline__ f32x4 mfma16(f16x8 a, f16x8 b, f32x4 c){
  return __builtin_amdgcn_mfma_f32_16x16x32_f16(a, b, c, 0, 0, 0);
}
// async global->LDS, 16 B per lane. LDS side must be wave-uniform base + lane*16.
__device__ __forceinline__ void glds16(const void* g, void* l){
  __builtin_amdgcn_global_load_lds((const __attribute__((address_space(1))) unsigned*)g,
                                   (__attribute__((address_space(3))) unsigned*)l, 16, 0, 0);
}

// ---------------- elementwise fp32 -> fp16 ----------------
__global__ __launch_bounds__(256) void split_kernel(const float* __restrict__ in,
    unsigned short* __restrict__ out, int n){
  int i = blockIdx.x*256 + threadIdx.x;
  if (i >= n) return;
  out[i] = f2h(in[i]);
}

// ---------------- tiled transpose + convert: in [mat][R][C] f32 -> out [mat][C][R] fp16 ----------------
__global__ __launch_bounds__(256) void transp_kernel(const float* __restrict__ in,
    unsigned short* __restrict__ out,
    int R, int C, long inStride, long outStride){
  const float* ip = in + (long)blockIdx.z * inStride;
  long ob = (long)blockIdx.z * outStride;
  __shared__ float tile[32][33];
  int c0 = blockIdx.x*32, r0 = blockIdx.y*32;
  int tx = threadIdx.x, ty = threadIdx.y;
  for (int i = ty; i < 32; i += 8)
    tile[i][tx] = ip[(long)(r0+i)*C + c0 + tx];
  __syncthreads();
  int t  = tx + ty*32;
  int sx = t & 15;        // r-pair index
  int sc = t >> 4;        // col group
  #pragma unroll
  for (int j = 0; j < 2; j++){
    int cc = sc + j*16;
    float v0 = tile[sx*2][cc], v1 = tile[sx*2+1][cc];
    long oidx = ob + (long)(c0+cc)*R + r0 + sx*2;
    unsigned uh = (unsigned)f2h(v0) | ((unsigned)f2h(v1) << 16);
    *(unsigned*)(out + oidx) = uh;
  }
}

// ---------------- generic 128x128x32 fp16 MFMA GEMM, B^T ("Bt[n][k]") layout ----------------
// MODE: 0=QKV  1=WO  4=WD
struct GemmP {
  const unsigned short* A;
  const unsigned short* B;
  int M, N, K;
  const float* bias;  const float* bias2; const float* bias3;
  const float* resid;
  float* outF;
  unsigned short* outBF;
  unsigned short *qh,*kh,*vth;
  const int* pair_token;
  const float* pair_w;
  const int* cnt;
  const int* offs;
  const int* tile_e;
  const int* tile_m;
  const int* ntiles;
};

template<int MODE>
__global__ __launch_bounds__(256, 2) void gemm_bt(GemmP p){
  const int tid  = threadIdx.x;
  const int lane = tid & 63;
  const int wave = tid >> 6;
  const int quad = lane >> 4;
  const int ln   = lane & 15;
  const int wr = wave >> 1, wc = wave & 1;
  const int bn0 = blockIdx.x * 128;
  const int bm0 = blockIdx.y * 128;
  const int K = p.K;

  long aoff[2]; long boff[2]; int koff[2];
  #pragma unroll
  for (int j = 0; j < 2; j++){
    int c = tid + j*256;
    int row = c >> 2;
    koff[j] = (c & 3) * 8;
    aoff[j] = (long)(bm0 + row) * K;
    boff[j] = (long)(bn0 + row) * K;
  }

  // double-buffered stages: issue next-tile loads before compute (latency hides under MFMA)
  __shared__ __align__(16) unsigned short As[2][128*32];
  __shared__ __align__(16) unsigned short Bs[2][128*32];

  auto stage = [&](int k0, int buf){
    #pragma unroll
    for (int j = 0; j < 2; j++){
      int c = tid + j*256;
      glds16(p.A + aoff[j] + k0 + koff[j], &As[buf][c*8]);
      glds16(p.B + boff[j] + k0 + koff[j], &Bs[buf][c*8]);
    }
  };

  f32x4 zero4 = {0.f, 0.f, 0.f, 0.f};
  f32x4 acc[4][4];
  #pragma unroll
  for (int i = 0; i < 4; i++)
    #pragma unroll
    for (int j = 0; j < 4; j++) acc[i][j] = zero4;

  stage(0, 0);
  __syncthreads();          // drains vmcnt(0): tile 0 resident
  int cur = 0;

  for (int k0 = 0; k0 < K; k0 += 32){
    if (k0 + 32 < K) stage(k0 + 32, cur ^ 1);
    f16x8 af[4], bfr[4];
    #pragma unroll
    for (int mt = 0; mt < 4; mt++)
      af[mt] = *(const f16x8*)&As[cur][(wr*64 + mt*16 + ln)*32 + quad*8];
    #pragma unroll
    for (int nt = 0; nt < 4; nt++)
      bfr[nt] = *(const f16x8*)&Bs[cur][(wc*64 + nt*16 + ln)*32 + quad*8];
    #pragma unroll
    for (int mt = 0; mt < 4; mt++)
      #pragma unroll
      for (int nt = 0; nt < 4; nt++)
        acc[mt][nt] = mfma16(af[mt], bfr[nt], acc[mt][nt]);
    __syncthreads();        // next tile landed; protects buffer reuse
    cur ^= 1;
  }

  #pragma unroll
  for (int mt = 0; mt < 4; mt++){
    #pragma unroll
    for (int nt = 0; nt < 4; nt++){
      #pragma unroll
      for (int r = 0; r < 4; r++){
        int gm = bm0 + wr*64 + mt*16 + quad*4 + r;
        int gn = bn0 + wc*64 + nt*16 + ln;
        float v = acc[mt][nt][r];
        if (MODE == 0){
          int which = gn >= 1536 ? 2 : (gn >= 768 ? 1 : 0);
          int nn = gn - which*768;
          int hh = nn >> 6, dh = nn & 63;
          if (which == 0){
            float q = (v + p.bias[nn]) * 0.125f;
            long o = ((long)hh*S_LEN + gm)*64 + dh;
            p.qh[o] = f2h(q);
          } else if (which == 1){
            float kv = v + p.bias2[nn];
            long o = ((long)hh*S_LEN + gm)*64 + dh;
            p.kh[o] = f2h(kv);
          } else {
            float vv = v + p.bias3[nn];
            long o = ((long)hh*64 + dh)*S_LEN + gm;   // V^T: [h][d][s]
            p.vth[o] = f2h(vv);
          }
        } else if (MODE == 1 || MODE == 4){
          long i = (long)gm*DMODEL + gn;
          p.outF[i] = v + p.bias[gn] + p.resid[i];
        }
      }
    }
  }
}

// ---------------- 256M x 128N MoE GEMM, 512 threads / 8 waves ----------------
// Compacted tile list (blockIdx.y -> (expert, m0)) + double-buffered prefetch pipeline.
// MODE: 2=MOE1(gather A by pair_token)  3=MOE2(contiguous pair rows)
template<int MODE>
__global__ __launch_bounds__(512, 4) void gemm_big(GemmP p){
  const int ty = blockIdx.y;
  if (ty >= *p.ntiles) return;
  const int e   = p.tile_e[ty];
  const int bm0 = p.tile_m[ty];

  const int tid  = threadIdx.x;
  const int lane = tid & 63;
  const int wave = tid >> 6;          // 0..7, 4x2 (wr x wc)
  const int quad = lane >> 4;
  const int ln   = lane & 15;
  const int wr = wave >> 1, wc = wave & 1;
  const int bn0 = blockIdx.x * 128;
  const int K = p.K;

  const int eoff = p.offs[e];
  const int Mloc = p.cnt[e];
  const unsigned short* Bp = p.B + (long)e * FDIM * DMODEL;

  long aoff[2]; int koffA[2];
  #pragma unroll
  for (int j = 0; j < 2; j++){
    int c = tid + j*512;
    int row = c >> 2;
    koffA[j] = (c & 3) * 8;
    int r = bm0 + row; if (r >= Mloc) r = Mloc - 1;
    aoff[j] = (MODE == 2) ? (long)p.pair_token[eoff + r] * K : (long)(eoff + r) * K;
  }
  long boff; int koffB;
  {
    int row = tid >> 2;
    koffB = (tid & 3) * 8;
    boff = (long)(bn0 + row) * K;
  }

  __shared__ __align__(16) unsigned short As[2][256*32];
  __shared__ __align__(16) unsigned short Bs[2][128*32];

  auto stage = [&](int k0, int buf){
    #pragma unroll
    for (int j = 0; j < 2; j++){
      int c = tid + j*512;
      glds16(p.A + aoff[j] + k0 + koffA[j], &As[buf][c*8]);
    }
    glds16(Bp + boff + k0 + koffB, &Bs[buf][tid*8]);
  };

  f32x4 zero4 = {0.f, 0.f, 0.f, 0.f};
  f32x4 acc[4][4];
  #pragma unroll
  for (int i = 0; i < 4; i++)
    #pragma unroll
    for (int j = 0; j < 4; j++) acc[i][j] = zero4;

  stage(0, 0);
  __syncthreads();
  int cur = 0;

  for (int k0 = 0; k0 < K; k0 += 32){
    if (k0 + 32 < K) stage(k0 + 32, cur ^ 1);
    f16x8 af[4], bfr[4];
    #pragma unroll
    for (int mt = 0; mt < 4; mt++)
      af[mt] = *(const f16x8*)&As[cur][(wr*64 + mt*16 + ln)*32 + quad*8];
    #pragma unroll
    for (int nt = 0; nt < 4; nt++)
      bfr[nt] = *(const f16x8*)&Bs[cur][(wc*64 + nt*16 + ln)*32 + quad*8];
    #pragma unroll
    for (int mt = 0; mt < 4; mt++)
      #pragma unroll
      for (int nt = 0; nt < 4; nt++)
        acc[mt][nt] = mfma16(af[mt], bfr[nt], acc[mt][nt]);
    __syncthreads();
    cur ^= 1;
  }

  #pragma unroll
  for (int mt = 0; mt < 4; mt++){
    #pragma unroll
    for (int nt = 0; nt < 4; nt++){
      #pragma unroll
      for (int r = 0; r < 4; r++){
        int gm = bm0 + wr*64 + mt*16 + quad*4 + r;
        int gn = bn0 + wc*64 + nt*16 + ln;
        if (gm < Mloc){
          float v = acc[mt][nt][r];
          if (MODE == 2){
            v = gelu_f(v + p.bias[(long)e*FDIM + gn]);
            p.outBF[(long)(eoff + gm)*FDIM + gn] = f2h(v);
          } else {
            int pi = eoff + gm;
            p.outF[(long)pi*DMODEL + gn] = v + p.bias[(long)e*DMODEL + gn];
          }
        }
      }
    }
  }
}

// ---------------- MFMA sliding-window attention, fp16 single-plane ----------------
// grid (16 chunks, 12 heads, 4 strips of 64 q); block 256 (4 waves x 16-q sub-strip)
__global__ __launch_bounds__(256) void attn_mfma(
    const unsigned short* __restrict__ Qh,
    const unsigned short* __restrict__ Kh,
    const unsigned short* __restrict__ Vth,
    unsigned short* __restrict__ attn_h){
  const int c = blockIdx.x, h = blockIdx.y, qb = blockIdx.z;
  const int tid = threadIdx.x;
  const int lane = tid & 63, w = tid >> 6;
  const int quad = lane >> 4, ln = lane & 15;
  const int q0 = c*256 + qb*64;
  const int qw = q0 + w*16;

  __shared__ __align__(16) unsigned short Ks[64*64];
  __shared__ __align__(16) unsigned short Vs[64*64];
  __shared__ __align__(16) unsigned short Ps[4][16*72];

  f16x8 qf[2];
  {
    long qrow = ((long)h*S_LEN + qw + ln)*64 + quad*8;
    qf[0] = *(const f16x8*)(Qh + qrow);
    qf[1] = *(const f16x8*)(Qh + qrow + 32);
  }

  float m_s[4], l_s[4];
  f32x4 Oc[4];
  f32x4 z4 = {0.f,0.f,0.f,0.f};
  #pragma unroll
  for (int r = 0; r < 4; r++){ m_s[r] = -1e30f; l_s[r] = 0.f; }
  #pragma unroll
  for (int nt = 0; nt < 4; nt++) Oc[nt] = z4;

  const unsigned short* KB = Kh + (long)h*S_LEN*64;
  const unsigned short* VB = Vth + (long)h*64*S_LEN;

  for (int kb = 0; kb < 12; kb++){
    const int kstart = c*256 - 256 + kb*64;
    if (kstart + 63 < 0 || kstart >= S_LEN) continue;
    if (kstart + 63 < q0 - 256 || kstart > q0 + 63 + 256) continue;
    __syncthreads();
    #pragma unroll
    for (int p2 = 0; p2 < 2; p2++){
      int idx = p2*256 + tid;
      int row = idx >> 3;
      int pc  = idx & 7;
      int lc  = pc ^ (row & 7);
      int ka = kstart + row;
      int kac = ka < 0 ? 0 : (ka > S_LEN-1 ? S_LEN-1 : ka);
      long gK = (long)kac*64 + lc*8;
      glds16(KB + gK, &Ks[idx*8]);
      int ks0 = kstart + lc*8;
      ks0 = ks0 < 0 ? 0 : (ks0 > S_LEN-8 ? S_LEN-8 : ks0);
      long gV = (long)row*S_LEN + ks0;
      glds16(VB + gV, &Vs[idx*8]);
    }
    __syncthreads();
    if (kstart + 63 < qw - 256 || kstart > qw + 15 + 256) continue;

    f32x4 Sc[4];
    #pragma unroll
    for (int nt = 0; nt < 4; nt++) Sc[nt] = z4;
    #pragma unroll
    for (int kc = 0; kc < 2; kc++){
      f16x8 bh[4];
      #pragma unroll
      for (int nt = 0; nt < 4; nt++){
        int row = nt*16 + ln;
        int o = row*64 + (((kc*4 + quad) ^ (row & 7))*8);
        bh[nt] = *(const f16x8*)&Ks[o];
      }
      #pragma unroll
      for (int nt = 0; nt < 4; nt++)
        Sc[nt] = mfma16(qf[kc], bh[nt], Sc[nt]);
    }
    bool interior = (kstart >= qw - 241) && (kstart <= qw + 193) &&
                    (kstart >= 0) && (kstart + 63 <= S_LEN - 1);
    if (!interior){
      #pragma unroll
      for (int nt = 0; nt < 4; nt++){
        int ka = kstart + nt*16 + ln;
        #pragma unroll
        for (int r = 0; r < 4; r++){
          int qa = qw + quad*4 + r;
          bool v = (ka >= 0) && (ka < S_LEN) && (ka >= qa - 256) && (ka <= qa + 256);
          if (!v) Sc[nt][r] = -3.0e38f;
        }
      }
    }
    float bm[4];
    #pragma unroll
    for (int r = 0; r < 4; r++)
      bm[r] = fmaxf(fmaxf(Sc[0][r], Sc[1][r]), fmaxf(Sc[2][r], Sc[3][r]));
    #pragma unroll
    for (int off = 1; off < 16; off <<= 1)
      #pragma unroll
      for (int r = 0; r < 4; r++) bm[r] = fmaxf(bm[r], __shfl_xor(bm[r], off));
    float al[4];
    #pragma unroll
    for (int r = 0; r < 4; r++){
      float mnew = fmaxf(m_s[r], bm[r]);
      al[r] = __expf(m_s[r] - mnew);
      m_s[r] = mnew;
    }
    float psum[4] = {0.f,0.f,0.f,0.f};
    #pragma unroll
    for (int nt = 0; nt < 4; nt++){
      #pragma unroll
      for (int r = 0; r < 4; r++){
        float pv = __expf(Sc[nt][r] - m_s[r]);
        psum[r] += pv;
        int o = (quad*4 + r)*72 + nt*16 + ln;
        Ps[w][o] = f2h(pv);
      }
    }
    #pragma unroll
    for (int off = 1; off < 16; off <<= 1)
      #pragma unroll
      for (int r = 0; r < 4; r++) psum[r] += __shfl_xor(psum[r], off);
    #pragma unroll
    for (int r = 0; r < 4; r++) l_s[r] = l_s[r]*al[r] + psum[r];
    #pragma unroll
    for (int nt = 0; nt < 4; nt++)
      #pragma unroll
      for (int r = 0; r < 4; r++) Oc[nt][r] *= al[r];
    asm volatile("s_waitcnt lgkmcnt(0)" ::: "memory");
    #pragma unroll
    for (int kc = 0; kc < 2; kc++){
      f16x8 ph = *(const f16x8*)&Ps[w][ln*72 + kc*32 + quad*8];
      #pragma unroll
      for (int nt = 0; nt < 4; nt++){
        int row = nt*16 + ln;
        int o = row*64 + (((kc*4 + quad) ^ (row & 7))*8);
        f16x8 vh = *(const f16x8*)&Vs[o];
        Oc[nt] = mfma16(ph, vh, Oc[nt]);
      }
    }
  }
  float inv[4];
  #pragma unroll
  for (int r = 0; r < 4; r++) inv[r] = 1.f / l_s[r];
  #pragma unroll
  for (int nt = 0; nt < 4; nt++){
    #pragma unroll
    for (int r = 0; r < 4; r++){
      int qa = qw + quad*4 + r;
      long o = (long)qa*DMODEL + h*64 + nt*16 + ln;
      attn_h[o] = f2h(Oc[nt][r] * inv[r]);
    }
  }
}

// ---------------- LayerNorm (fp32), optional fp16 copy ----------------
__global__ __launch_bounds__(256) void ln_kernel(const float* __restrict__ x,
    const float* __restrict__ g, const float* __restrict__ b,
    float* __restrict__ outF, unsigned short* __restrict__ outH){
  int s = blockIdx.x;
  const float* row = x + (long)s*DMODEL;
  int t = threadIdx.x;
  float v0 = row[t], v1 = row[t+256], v2 = row[t+512];
  float sum = v0+v1+v2;
  float sq  = v0*v0 + v1*v1 + v2*v2;
  for (int o = 32; o > 0; o >>= 1){ sum += __shfl_xor(sum, o); sq += __shfl_xor(sq, o); }
  __shared__ float s1[4], s2[4];
  int wv = t >> 6;
  if ((t & 63) == 0){ s1[wv] = sum; s2[wv] = sq; }
  __syncthreads();
  sum = s1[0]+s1[1]+s1[2]+s1[3];
  sq  = s2[0]+s2[1]+s2[2]+s2[3];
  float mean = sum * (1.0f/DMODEL);
  float var  = sq  * (1.0f/DMODEL) - mean*mean;
  float inv = rsqrtf(var + 1e-5f);
  float* orow = outF + (long)s*DMODEL;
  unsigned short* hrow = outH ? outH + (long)s*DMODEL : (unsigned short*)0;
  #pragma unroll
  for (int j = 0; j < 3; j++){
    int d = t + j*256;
    float y = (row[d] - mean) * inv * g[d] + b[d];
    orow[d] = y;
    if (hrow) hrow[d] = f2h(y);
  }
}

// ---------------- gate: wave-per-token GEMV, top-2 softmax. NO atomics. ----------------
__global__ __launch_bounds__(256) void gate_kernel(const float* __restrict__ x,
    const float* __restrict__ gw, const float* __restrict__ gb,
    float* __restrict__ gate_out, int* __restrict__ tok_e,
    float* __restrict__ tok_w){
  int w = threadIdx.x >> 6;
  int lane = threadIdx.x & 63;
  int s = blockIdx.x*4 + w;
  float acc[NEXP];
  #pragma unroll
  for (int e = 0; e < NEXP; e++) acc[e] = 0.f;
  const float* xr = x + (long)s*DMODEL;
  #pragma unroll
  for (int j = 0; j < DMODEL/64; j++){
    int d = lane + j*64;
    float xv = xr[d];
    const float* wr = gw + (long)d*NEXP;
    #pragma unroll
    for (int e = 0; e < NEXP; e++) acc[e] += xv * wr[e];
  }
  #pragma unroll
  for (int e = 0; e < NEXP; e++){
    float v = acc[e];
    for (int o = 32; o > 0; o >>= 1) v += __shfl_xor(v, o);
    acc[e] = v;
  }
  if (lane == 0){
    #pragma unroll
    for (int e = 0; e < NEXP; e++) acc[e] += gb[e];
    int i0 = 0;
    for (int e = 1; e < NEXP; e++) if (acc[e] > acc[i0]) i0 = e;
    int i1 = -1;
    for (int e = 0; e < NEXP; e++) if (e != i0 && (i1 < 0 || acc[e] > acc[i1])) i1 = e;
    float e1 = expf(acc[i1] - acc[i0]);
    float inv = 1.f / (1.f + e1);
    float w0 = inv, w1 = e1 * inv;
    float* go = gate_out + (long)s*NEXP;
    #pragma unroll
    for (int e = 0; e < NEXP; e++) go[e] = 0.f;
    go[i0] = w0; go[i1] = w1;
    tok_e[s*2] = i0; tok_e[s*2+1] = i1;
    tok_w[s*2] = w0; tok_w[s*2+1] = w1;
  }
}

// ---------------- route: single-block deterministic counting sort over 8192 slots ----------------
// Replaces scan+scatter. LDS histograms (stride 7 -> <=2-way bank alias, free), no global atomics.
__global__ __launch_bounds__(256) void route_kernel(const int* __restrict__ tok_e,
    const float* __restrict__ tok_w,
    int* __restrict__ cnt, int* __restrict__ offs,
    int* __restrict__ pair_token, float* __restrict__ pair_w, int* __restrict__ tok_pi,
    int* __restrict__ tile_e, int* __restrict__ tile_m, int* __restrict__ ntiles){
  __shared__ int hist[256][NEXP];
  __shared__ int cntS[NEXP], offsS[NEXP];
  const int t = threadIdx.x;
  const int CH = NPAIR/256;   // 32 slots per thread
  const int base = t*CH;
  #pragma unroll
  for (int e = 0; e < NEXP; e++) hist[t][e] = 0;
  for (int i = 0; i < CH; i++)
    hist[t][tok_e[base+i]]++;
  __syncthreads();
  // per-expert exclusive scan across threads (7 threads, sequential over 256)
  if (t < NEXP){
    int s = 0;
    for (int i = 0; i < 256; i++){ int v = hist[i][t]; hist[i][t] = s; s += v; }
    cntS[t] = s;
  }
  __syncthreads();
  if (t == 0){
    int s = 0, tt = 0;
    for (int e = 0; e < NEXP; e++){ offsS[e] = s; s += cntS[e]; }
    for (int e = 0; e < NEXP; e++)
      for (int m0 = 0; m0 < cntS[e]; m0 += 256){ tile_e[tt] = e; tile_m[tt] = m0; tt++; }
    *ntiles = tt;
    for (int e = 0; e < NEXP; e++){ cnt[e] = cntS[e]; offs[e] = offsS[e]; }
  }
  __syncthreads();
  // stable assignment: pos = offs[e] + prefix[t][e] + local running rank
  for (int i = 0; i < CH; i++){
    int idx = base + i;
    int e = tok_e[idx];
    int pi = offsS[e] + hist[t][e]++;
    pair_token[pi] = idx >> 1;
    pair_w[pi] = tok_w[idx];
    tok_pi[idx] = pi;
  }
}

// ---------------- combine: moe[t] = w0*P[p0] + w1*P[p1] -> fp16 ----------------
__global__ __launch_bounds__(256) void combine_kernel(const float* __restrict__ Pbuf,
    const int* __restrict__ tok_pi, const float* __restrict__ tok_w,
    unsigned short* __restrict__ moe_h){
  int t = blockIdx.x;
  int d = threadIdx.x;
  float w0 = tok_w[t*2], w1 = tok_w[t*2+1];
  long p0 = (long)tok_pi[t*2]   * DMODEL;
  long p1 = (long)tok_pi[t*2+1] * DMODEL;
  unsigned short* orow = moe_h + (long)t*DMODEL;
  #pragma unroll
  for (int j = 0; j < 3; j++){
    int dd = d + j*256;
    orow[dd] = f2h(w0*Pbuf[p0+dd] + w1*Pbuf[p1+dd]);
  }
}

// ---------------- host launch ----------------
extern "C" void kernel_launch(void* const* d_in, const int* in_sizes, int n_in,
                              void* d_out, int out_size, void* d_ws, size_t ws_size,
                              hipStream_t stream){
  (void)in_sizes; (void)n_in; (void)out_size; (void)ws_size;
  const float* hidden = (const float*)d_in[0];
  const float* Wq  = (const float*)d_in[1];
  const float* bq  = (const float*)d_in[2];
  const float* Wk  = (const float*)d_in[3];
  const float* bk  = (const float*)d_in[4];
  const float* Wv  = (const float*)d_in[5];
  const float* bv  = (const float*)d_in[6];
  const float* Wo  = (const float*)d_in[7];
  const float* bo  = (const float*)d_in[8];
  const float* ln1g = (const float*)d_in[9];
  const float* ln1b = (const float*)d_in[10];
  const float* gateW = (const float*)d_in[11];
  const float* gateB = (const float*)d_in[12];
  const float* W1e = (const float*)d_in[13];
  const float* b1e = (const float*)d_in[14];
  const float* W2e = (const float*)d_in[15];
  const float* b2e = (const float*)d_in[16];
  const float* Wd  = (const float*)d_in[17];
  const float* bd  = (const float*)d_in[18];
  const float* ln2g = (const float*)d_in[19];
  const float* ln2b = (const float*)d_in[20];

  float* outL = (float*)d_out;
  float* outG = outL + (size_t)S_LEN*DMODEL;

  const size_t SD = (size_t)S_LEN*DMODEL;
  char* base = (char*)d_ws;
  size_t off = 0;
  auto alloc = [&](size_t bytes)->void*{
    void* r = base + off;
    off = (off + bytes + 255) & ~(size_t)255;
    return r;
  };
  unsigned short* x_h     = (unsigned short*)alloc(SD*2);
  unsigned short* wqkv_h  = (unsigned short*)alloc((size_t)2304*768*2);
  unsigned short* wo_h    = (unsigned short*)alloc((size_t)768*768*2);
  unsigned short* wd_h    = (unsigned short*)alloc((size_t)768*768*2);
  unsigned short* w1_h    = (unsigned short*)alloc((size_t)NEXP*FDIM*DMODEL*2);
  unsigned short* w2_h    = (unsigned short*)alloc((size_t)NEXP*FDIM*DMODEL*2);
  unsigned short* q_h   = (unsigned short*)alloc(SD*2);
  unsigned short* k_h   = (unsigned short*)alloc(SD*2);
  unsigned short* vt_h  = (unsigned short*)alloc(SD*2);
  unsigned short* attn_h = (unsigned short*)alloc(SD*2);
  float* preLN1    = (float*)alloc(SD*4);
  float* attnout_f = (float*)alloc(SD*4);
  unsigned short* attnout_h = (unsigned short*)alloc(SD*2);
  int*   tok_e = (int*)alloc(2*S_LEN*4);
  float* tok_w = (float*)alloc(2*S_LEN*4);
  int*   tok_pi = (int*)alloc(2*S_LEN*4);
  int*   cnt   = (int*)alloc(32*4);
  int*   offs  = (int*)alloc(32*4);
  int*   tile_e = (int*)alloc(MAXTILES*4);
  int*   tile_m = (int*)alloc(MAXTILES*4);
  int*   ntiles = (int*)alloc(4);
  int*   pair_token = (int*)alloc(NPAIR*4);
  float* pair_w     = (float*)alloc(NPAIR*4);
  unsigned short* Hbuf = (unsigned short*)alloc((size_t)NPAIR*FDIM*2);
  float* Pbuf = (float*)alloc((size_t)NPAIR*DMODEL*4);
  unsigned short* moe_h = (unsigned short*)alloc(SD*2);
  float* preLN2 = preLN1;

  // 1. hidden -> fp16
  split_kernel<<<dim3((unsigned)(SD/256)), dim3(256), 0, stream>>>(hidden, x_h, (int)SD);
  // 2. weight transposes/converts (all single-plane fp16)
  transp_kernel<<<dim3(24,24,1), dim3(32,8), 0, stream>>>(Wq, wqkv_h,           DMODEL, DMODEL, 0, 0);
  transp_kernel<<<dim3(24,24,1), dim3(32,8), 0, stream>>>(Wk, wqkv_h+768*768,   DMODEL, DMODEL, 0, 0);
  transp_kernel<<<dim3(24,24,1), dim3(32,8), 0, stream>>>(Wv, wqkv_h+2*768*768, DMODEL, DMODEL, 0, 0);
  transp_kernel<<<dim3(24,24,1), dim3(32,8), 0, stream>>>(Wo, wo_h, DMODEL, DMODEL, 0, 0);
  transp_kernel<<<dim3(24,24,1), dim3(32,8), 0, stream>>>(Wd, wd_h, DMODEL, DMODEL, 0, 0);
  transp_kernel<<<dim3(96,24,NEXP), dim3(32,8), 0, stream>>>(W1e, w1_h, DMODEL, FDIM, (long)DMODEL*FDIM, (long)DMODEL*FDIM);
  transp_kernel<<<dim3(24,96,NEXP), dim3(32,8), 0, stream>>>(W2e, w2_h, FDIM, DMODEL, (long)DMODEL*FDIM, (long)DMODEL*FDIM);

  // 3. QKV projection -> Q,K [h][s][64]; V transposed [h][d][s]  (fp16)
  GemmP pq = {};
  pq.A = x_h; pq.B = wqkv_h;
  pq.M = S_LEN; pq.N = 2304; pq.K = DMODEL;
  pq.bias = bq; pq.bias2 = bk; pq.bias3 = bv;
  pq.qh = q_h; pq.kh = k_h; pq.vth = vt_h;
  gemm_bt<0><<<dim3(18,32,1), dim3(256), 0, stream>>>(pq);

  // 4. MFMA attention -> attn fp16
  attn_mfma<<<dim3(16,NHEADS,4), dim3(256), 0, stream>>>(q_h, k_h, vt_h, attn_h);

  // 5. Wo projection + bias + residual -> preLN1 (fp32)
  GemmP pw = {};
  pw.A = attn_h; pw.B = wo_h;
  pw.M = S_LEN; pw.N = DMODEL; pw.K = DMODEL;
  pw.bias = bo; pw.resid = hidden; pw.outF = preLN1;
  gemm_bt<1><<<dim3(6,32,1), dim3(256), 0, stream>>>(pw);

  // 6. LN1 -> attnout (fp32 + fp16)
  ln_kernel<<<dim3(S_LEN), dim3(256), 0, stream>>>(preLN1, ln1g, ln1b, attnout_f, attnout_h);

  // 7. gate (no atomics) + deterministic route (replaces memset/scan/scatter)
  gate_kernel<<<dim3(S_LEN/4), dim3(256), 0, stream>>>(attnout_f, gateW, gateB, outG, tok_e, tok_w);
  route_kernel<<<dim3(1), dim3(256), 0, stream>>>(tok_e, tok_w, cnt, offs,
      pair_token, pair_w, tok_pi, tile_e, tile_m, ntiles);

  // 8. MoE expert GEMMs (top-2 sparse), 256M x 128N shared-stage blocks, compacted tiles
  GemmP p1 = {};
  p1.A = attnout_h; p1.B = w1_h; p1.M = S_LEN; p1.N = FDIM; p1.K = DMODEL;
  p1.bias = b1e; p1.outBF = Hbuf;
  p1.pair_token = pair_token; p1.cnt = cnt; p1.offs = offs;
  p1.tile_e = tile_e; p1.tile_m = tile_m; p1.ntiles = ntiles;
  gemm_big<2><<<dim3(24,MAXTILES), dim3(512), 0, stream>>>(p1);

  GemmP p2 = {};
  p2.A = Hbuf; p2.B = w2_h; p2.M = S_LEN; p2.N = DMODEL; p2.K = FDIM;
  p2.bias = b2e; p2.outF = Pbuf;
  p2.pair_token = pair_token; p2.pair_w = pair_w; p2.cnt = cnt; p2.offs = offs;
  p2.tile_e = tile_e; p2.tile_m = tile_m; p2.ntiles = ntiles;
  gemm_big<3><<<dim3(6,MAXTILES), dim3(512), 0, stream>>>(p2);

  // 9. combine pairs -> moe fp16; Wd + bias + residual(attention_output) -> preLN2
  combine_kernel<<<dim3(S_LEN), dim3(256), 0, stream>>>(Pbuf, tok_pi, tok_w, moe_h);
  GemmP pd = {};
  pd.A = moe_h; pd.B = wd_h; pd.M = S_LEN; pd.N = DMODEL; pd.K = DMODEL;
  pd.bias = bd; pd.resid = attnout_f; pd.outF = preLN2;
  gemm_bt<4><<<dim3(6,32,1), dim3(256), 0, stream>>>(pd);

  // 10. LN2 -> layer_output
  ln_kernel<<<dim3(S_LEN), dim3(256), 0, stream>>>(preLN2, ln2g, ln2b, outL, nullptr);
}

// Round 4
// 589.198 us; speedup vs baseline: 1.4311x; 1.0344x over previous
//
#include <hip/hip_runtime.h>
#include <math.h>

#define S_LEN 4096
#define DMODEL 768
#define NHEADS 12
#define DH 64
#define FDIM 3072
#define NEXP 7
#define NPAIR (2*S_LEN)
#define MAXTILES 40

typedef _Float16 f16x8 __attribute__((ext_vector_type(8)));
typedef float f32x4 __attribute__((ext_vector_type(4)));

__device__ __forceinline__ unsigned short f2h(float f){
  union { _Float16 h; unsigned short u; } v; v.h = (_Float16)f; return v.u;
}
__device__ __forceinline__ float gelu_f(float x){
  return 0.5f * x * (1.0f + erff(x * 0.7071067811865475f));
}
__device__ __forceinline__ f32x4 mfma16(f16x8 a, f16x8 b, f32x4 c){
  return __builtin_amdgcn_mfma_f32_16x16x32_f16(a, b, c, 0, 0, 0);
}
// async global->LDS, 16 B per lane. LDS side must be wave-uniform base + lane*16.
__device__ __forceinline__ void glds16(const void* g, void* l){
  __builtin_amdgcn_global_load_lds((const __attribute__((address_space(1))) unsigned*)g,
                                   (__attribute__((address_space(3))) unsigned*)l, 16, 0, 0);
}
// bijective XCD chunk swizzle: consecutive logical ids land on the SAME XCD.
// requires total % 8 == 0 (all our grids are).
__device__ __forceinline__ int xcd_logical(int lin, int total){
  int q = total >> 3;
  return (lin & 7)*q + (lin >> 3);
}

// ---------------- elementwise fp32 -> fp16 ----------------
__global__ __launch_bounds__(256) void split_kernel(const float* __restrict__ in,
    unsigned short* __restrict__ out, int n){
  int i = blockIdx.x*256 + threadIdx.x;
  if (i >= n) return;
  out[i] = f2h(in[i]);
}

// ---------------- tiled transpose + convert: in [mat][R][C] f32 -> out [mat][C][R] fp16 ----------------
__global__ __launch_bounds__(256) void transp_kernel(const float* __restrict__ in,
    unsigned short* __restrict__ out,
    int R, int C, long inStride, long outStride){
  const float* ip = in + (long)blockIdx.z * inStride;
  long ob = (long)blockIdx.z * outStride;
  __shared__ float tile[32][33];
  int c0 = blockIdx.x*32, r0 = blockIdx.y*32;
  int tx = threadIdx.x, ty = threadIdx.y;
  for (int i = ty; i < 32; i += 8)
    tile[i][tx] = ip[(long)(r0+i)*C + c0 + tx];
  __syncthreads();
  int t  = tx + ty*32;
  int sx = t & 15;        // r-pair index
  int sc = t >> 4;        // col group
  #pragma unroll
  for (int j = 0; j < 2; j++){
    int cc = sc + j*16;
    float v0 = tile[sx*2][cc], v1 = tile[sx*2+1][cc];
    long oidx = ob + (long)(c0+cc)*R + r0 + sx*2;
    unsigned uh = (unsigned)f2h(v0) | ((unsigned)f2h(v1) << 16);
    *(unsigned*)(out + oidx) = uh;
  }
}

// ---------------- generic 128x128x32 fp16 MFMA GEMM, B^T ("Bt[n][k]") layout ----------------
// Counted-vmcnt pipeline: stage t+2 issued while t+1 in flight; waits never hit 0 mid-loop.
// LDS chunk-XOR swizzle (pre-swizzled global source + swizzled read).
// MODE: 0=QKV  1=WO  4=WD
struct GemmP {
  const unsigned short* A;
  const unsigned short* B;
  int M, N, K;
  const float* bias;  const float* bias2; const float* bias3;
  const float* resid;
  float* outF;
  unsigned short* outBF;
  unsigned short *qh,*kh,*vth;
  const int* pair_token;
  const float* pair_w;
  const int* cnt;
  const int* offs;
  const int* tile_e;
  const int* tile_m;
  const int* ntiles;
};

template<int MODE>
__global__ __launch_bounds__(256, 2) void gemm_bt(GemmP p){
  const int tid  = threadIdx.x;
  const int lane = tid & 63;
  const int wave = tid >> 6;
  const int quad = lane >> 4;
  const int ln   = lane & 15;
  const int wr = wave >> 1, wc = wave & 1;
  // XCD chunk swizzle: by-major contiguity per XCD -> A-panel L2 reuse
  const int lin = blockIdx.y * gridDim.x + blockIdx.x;
  const int logical = xcd_logical(lin, gridDim.x*gridDim.y);
  const int bn0 = (logical % gridDim.x) * 128;
  const int bm0 = (logical / gridDim.x) * 128;
  const int K = p.K;

  long aoff[2]; long boff[2]; int koff[2];
  #pragma unroll
  for (int j = 0; j < 2; j++){
    int c = tid + j*256;
    int row = c >> 2;
    int pc  = c & 3;
    koff[j] = ((pc ^ (row & 3)) * 8);      // pre-swizzled global chunk
    aoff[j] = (long)(bm0 + row) * K;
    boff[j] = (long)(bn0 + row) * K;
  }

  __shared__ __align__(16) unsigned short As[2][128*32];
  __shared__ __align__(16) unsigned short Bs[2][128*32];

  auto stage = [&](int k0, int buf){
    #pragma unroll
    for (int j = 0; j < 2; j++){
      int c = tid + j*256;
      glds16(p.A + aoff[j] + k0 + koff[j], &As[buf][c*8]);
      glds16(p.B + boff[j] + k0 + koff[j], &Bs[buf][c*8]);
    }
  };

  f32x4 zero4 = {0.f, 0.f, 0.f, 0.f};
  f32x4 acc[4][4];
  #pragma unroll
  for (int i = 0; i < 4; i++)
    #pragma unroll
    for (int j = 0; j < 4; j++) acc[i][j] = zero4;

  stage(0, 0);
  stage(32, 1);            // K >= 64 always
  int cur = 0;

  for (int k0 = 0; k0 < K; k0 += 32){
    if (k0 + 32 < K) { asm volatile("s_waitcnt vmcnt(4)" ::: "memory"); }
    else             { asm volatile("s_waitcnt vmcnt(0)" ::: "memory"); }
    __builtin_amdgcn_sched_barrier(0);
    __builtin_amdgcn_s_barrier();          // all waves' stage-t writes visible

    f16x8 af[4], bfr[4];
    #pragma unroll
    for (int mt = 0; mt < 4; mt++)
      af[mt] = *(const f16x8*)&As[cur][(wr*64 + mt*16 + ln)*32 + ((quad ^ (ln & 3))*8)];
    #pragma unroll
    for (int nt = 0; nt < 4; nt++)
      bfr[nt] = *(const f16x8*)&Bs[cur][(wc*64 + nt*16 + ln)*32 + ((quad ^ (ln & 3))*8)];
    asm volatile("s_waitcnt lgkmcnt(0)" ::: "memory");
    __builtin_amdgcn_sched_barrier(0);
    __builtin_amdgcn_s_barrier();          // all waves done reading buf[cur]

    if (k0 + 64 < K) stage(k0 + 64, cur);  // overwrite-safe; 2 iters to land

    #pragma unroll
    for (int mt = 0; mt < 4; mt++)
      #pragma unroll
      for (int nt = 0; nt < 4; nt++)
        acc[mt][nt] = mfma16(af[mt], bfr[nt], acc[mt][nt]);
    cur ^= 1;
  }

  #pragma unroll
  for (int mt = 0; mt < 4; mt++){
    #pragma unroll
    for (int nt = 0; nt < 4; nt++){
      #pragma unroll
      for (int r = 0; r < 4; r++){
        int gm = bm0 + wr*64 + mt*16 + quad*4 + r;
        int gn = bn0 + wc*64 + nt*16 + ln;
        float v = acc[mt][nt][r];
        if (MODE == 0){
          int which = gn >= 1536 ? 2 : (gn >= 768 ? 1 : 0);
          int nn = gn - which*768;
          int hh = nn >> 6, dh = nn & 63;
          if (which == 0){
            float q = (v + p.bias[nn]) * 0.125f;
            long o = ((long)hh*S_LEN + gm)*64 + dh;
            p.qh[o] = f2h(q);
          } else if (which == 1){
            float kv = v + p.bias2[nn];
            long o = ((long)hh*S_LEN + gm)*64 + dh;
            p.kh[o] = f2h(kv);
          } else {
            float vv = v + p.bias3[nn];
            long o = ((long)hh*64 + dh)*S_LEN + gm;   // V^T: [h][d][s]
            p.vth[o] = f2h(vv);
          }
        } else if (MODE == 1 || MODE == 4){
          long i = (long)gm*DMODEL + gn;
          p.outF[i] = v + p.bias[gn] + p.resid[i];
        }
      }
    }
  }
}

// ---------------- 256M x 128N MoE GEMM, 512 threads / 8 waves ----------------
// Compacted tile list + counted-vmcnt pipeline + chunk swizzle + XCD chunking.
// MODE: 2=MOE1(gather A by pair_token)  3=MOE2(contiguous pair rows)
template<int MODE>
__global__ __launch_bounds__(512, 4) void gemm_big(GemmP p){
  const int lin = blockIdx.y * gridDim.x + blockIdx.x;
  const int logical = xcd_logical(lin, gridDim.x*gridDim.y);
  const int bx = logical % gridDim.x;
  const int ty = logical / gridDim.x;
  if (ty >= *p.ntiles) return;
  const int e   = p.tile_e[ty];
  const int bm0 = p.tile_m[ty];

  const int tid  = threadIdx.x;
  const int lane = tid & 63;
  const int wave = tid >> 6;          // 0..7, 4x2 (wr x wc)
  const int quad = lane >> 4;
  const int ln   = lane & 15;
  const int wr = wave >> 1, wc = wave & 1;
  const int bn0 = bx * 128;
  const int K = p.K;

  const int eoff = p.offs[e];
  const int Mloc = p.cnt[e];
  const unsigned short* Bp = p.B + (long)e * FDIM * DMODEL;

  long aoff[2]; int koffA[2];
  #pragma unroll
  for (int j = 0; j < 2; j++){
    int c = tid + j*512;
    int row = c >> 2;
    int pc  = c & 3;
    koffA[j] = ((pc ^ (row & 3)) * 8);
    int r = bm0 + row; if (r >= Mloc) r = Mloc - 1;
    aoff[j] = (MODE == 2) ? (long)p.pair_token[eoff + r] * K : (long)(eoff + r) * K;
  }
  long boff; int koffB;
  {
    int row = tid >> 2;
    int pc  = tid & 3;
    koffB = ((pc ^ (row & 3)) * 8);
    boff = (long)(bn0 + row) * K;
  }

  __shared__ __align__(16) unsigned short As[2][256*32];
  __shared__ __align__(16) unsigned short Bs[2][128*32];

  auto stage = [&](int k0, int buf){
    #pragma unroll
    for (int j = 0; j < 2; j++){
      int c = tid + j*512;
      glds16(p.A + aoff[j] + k0 + koffA[j], &As[buf][c*8]);
    }
    glds16(Bp + boff + k0 + koffB, &Bs[buf][tid*8]);
  };

  f32x4 zero4 = {0.f, 0.f, 0.f, 0.f};
  f32x4 acc[4][4];
  #pragma unroll
  for (int i = 0; i < 4; i++)
    #pragma unroll
    for (int j = 0; j < 4; j++) acc[i][j] = zero4;

  stage(0, 0);
  stage(32, 1);
  int cur = 0;

  for (int k0 = 0; k0 < K; k0 += 32){
    if (k0 + 32 < K) { asm volatile("s_waitcnt vmcnt(3)" ::: "memory"); }
    else             { asm volatile("s_waitcnt vmcnt(0)" ::: "memory"); }
    __builtin_amdgcn_sched_barrier(0);
    __builtin_amdgcn_s_barrier();

    f16x8 af[4], bfr[4];
    #pragma unroll
    for (int mt = 0; mt < 4; mt++)
      af[mt] = *(const f16x8*)&As[cur][(wr*64 + mt*16 + ln)*32 + ((quad ^ (ln & 3))*8)];
    #pragma unroll
    for (int nt = 0; nt < 4; nt++)
      bfr[nt] = *(const f16x8*)&Bs[cur][(wc*64 + nt*16 + ln)*32 + ((quad ^ (ln & 3))*8)];
    asm volatile("s_waitcnt lgkmcnt(0)" ::: "memory");
    __builtin_amdgcn_sched_barrier(0);
    __builtin_amdgcn_s_barrier();

    if (k0 + 64 < K) stage(k0 + 64, cur);

    #pragma unroll
    for (int mt = 0; mt < 4; mt++)
      #pragma unroll
      for (int nt = 0; nt < 4; nt++)
        acc[mt][nt] = mfma16(af[mt], bfr[nt], acc[mt][nt]);
    cur ^= 1;
  }

  #pragma unroll
  for (int mt = 0; mt < 4; mt++){
    #pragma unroll
    for (int nt = 0; nt < 4; nt++){
      #pragma unroll
      for (int r = 0; r < 4; r++){
        int gm = bm0 + wr*64 + mt*16 + quad*4 + r;
        int gn = bn0 + wc*64 + nt*16 + ln;
        if (gm < Mloc){
          float v = acc[mt][nt][r];
          if (MODE == 2){
            v = gelu_f(v + p.bias[(long)e*FDIM + gn]);
            p.outBF[(long)(eoff + gm)*FDIM + gn] = f2h(v);
          } else {
            int pi = eoff + gm;
            p.outF[(long)pi*DMODEL + gn] = v + p.bias[(long)e*DMODEL + gn];
          }
        }
      }
    }
  }
}

// ---------------- MFMA sliding-window attention, fp16 single-plane ----------------
// grid (16 chunks, 12 heads, 4 strips of 64 q); block 256 (4 waves x 16-q sub-strip)
__global__ __launch_bounds__(256) void attn_mfma(
    const unsigned short* __restrict__ Qh,
    const unsigned short* __restrict__ Kh,
    const unsigned short* __restrict__ Vth,
    unsigned short* __restrict__ attn_h){
  const int c = blockIdx.x, h = blockIdx.y, qb = blockIdx.z;
  const int tid = threadIdx.x;
  const int lane = tid & 63, w = tid >> 6;
  const int quad = lane >> 4, ln = lane & 15;
  const int q0 = c*256 + qb*64;
  const int qw = q0 + w*16;

  __shared__ __align__(16) unsigned short Ks[64*64];
  __shared__ __align__(16) unsigned short Vs[64*64];
  __shared__ __align__(16) unsigned short Ps[4][16*72];

  f16x8 qf[2];
  {
    long qrow = ((long)h*S_LEN + qw + ln)*64 + quad*8;
    qf[0] = *(const f16x8*)(Qh + qrow);
    qf[1] = *(const f16x8*)(Qh + qrow + 32);
  }

  float m_s[4], l_s[4];
  f32x4 Oc[4];
  f32x4 z4 = {0.f,0.f,0.f,0.f};
  #pragma unroll
  for (int r = 0; r < 4; r++){ m_s[r] = -1e30f; l_s[r] = 0.f; }
  #pragma unroll
  for (int nt = 0; nt < 4; nt++) Oc[nt] = z4;

  const unsigned short* KB = Kh + (long)h*S_LEN*64;
  const unsigned short* VB = Vth + (long)h*64*S_LEN;

  for (int kb = 0; kb < 12; kb++){
    const int kstart = c*256 - 256 + kb*64;
    if (kstart + 63 < 0 || kstart >= S_LEN) continue;
    if (kstart + 63 < q0 - 256 || kstart > q0 + 63 + 256) continue;
    __syncthreads();
    #pragma unroll
    for (int p2 = 0; p2 < 2; p2++){
      int idx = p2*256 + tid;
      int row = idx >> 3;
      int pc  = idx & 7;
      int lc  = pc ^ (row & 7);
      int ka = kstart + row;
      int kac = ka < 0 ? 0 : (ka > S_LEN-1 ? S_LEN-1 : ka);
      long gK = (long)kac*64 + lc*8;
      glds16(KB + gK, &Ks[idx*8]);
      int ks0 = kstart + lc*8;
      ks0 = ks0 < 0 ? 0 : (ks0 > S_LEN-8 ? S_LEN-8 : ks0);
      long gV = (long)row*S_LEN + ks0;
      glds16(VB + gV, &Vs[idx*8]);
    }
    __syncthreads();
    if (kstart + 63 < qw - 256 || kstart > qw + 15 + 256) continue;

    f32x4 Sc[4];
    #pragma unroll
    for (int nt = 0; nt < 4; nt++) Sc[nt] = z4;
    #pragma unroll
    for (int kc = 0; kc < 2; kc++){
      f16x8 bh[4];
      #pragma unroll
      for (int nt = 0; nt < 4; nt++){
        int row = nt*16 + ln;
        int o = row*64 + (((kc*4 + quad) ^ (row & 7))*8);
        bh[nt] = *(const f16x8*)&Ks[o];
      }
      #pragma unroll
      for (int nt = 0; nt < 4; nt++)
        Sc[nt] = mfma16(qf[kc], bh[nt], Sc[nt]);
    }
    bool interior = (kstart >= qw - 241) && (kstart <= qw + 193) &&
                    (kstart >= 0) && (kstart + 63 <= S_LEN - 1);
    if (!interior){
      #pragma unroll
      for (int nt = 0; nt < 4; nt++){
        int ka = kstart + nt*16 + ln;
        #pragma unroll
        for (int r = 0; r < 4; r++){
          int qa = qw + quad*4 + r;
          bool v = (ka >= 0) && (ka < S_LEN) && (ka >= qa - 256) && (ka <= qa + 256);
          if (!v) Sc[nt][r] = -3.0e38f;
        }
      }
    }
    float bm[4];
    #pragma unroll
    for (int r = 0; r < 4; r++)
      bm[r] = fmaxf(fmaxf(Sc[0][r], Sc[1][r]), fmaxf(Sc[2][r], Sc[3][r]));
    #pragma unroll
    for (int off = 1; off < 16; off <<= 1)
      #pragma unroll
      for (int r = 0; r < 4; r++) bm[r] = fmaxf(bm[r], __shfl_xor(bm[r], off));
    float al[4];
    #pragma unroll
    for (int r = 0; r < 4; r++){
      float mnew = fmaxf(m_s[r], bm[r]);
      al[r] = __expf(m_s[r] - mnew);
      m_s[r] = mnew;
    }
    float psum[4] = {0.f,0.f,0.f,0.f};
    #pragma unroll
    for (int nt = 0; nt < 4; nt++){
      #pragma unroll
      for (int r = 0; r < 4; r++){
        float pv = __expf(Sc[nt][r] - m_s[r]);
        psum[r] += pv;
        int o = (quad*4 + r)*72 + nt*16 + ln;
        Ps[w][o] = f2h(pv);
      }
    }
    #pragma unroll
    for (int off = 1; off < 16; off <<= 1)
      #pragma unroll
      for (int r = 0; r < 4; r++) psum[r] += __shfl_xor(psum[r], off);
    #pragma unroll
    for (int r = 0; r < 4; r++) l_s[r] = l_s[r]*al[r] + psum[r];
    #pragma unroll
    for (int nt = 0; nt < 4; nt++)
      #pragma unroll
      for (int r = 0; r < 4; r++) Oc[nt][r] *= al[r];
    asm volatile("s_waitcnt lgkmcnt(0)" ::: "memory");
    #pragma unroll
    for (int kc = 0; kc < 2; kc++){
      f16x8 ph = *(const f16x8*)&Ps[w][ln*72 + kc*32 + quad*8];
      #pragma unroll
      for (int nt = 0; nt < 4; nt++){
        int row = nt*16 + ln;
        int o = row*64 + (((kc*4 + quad) ^ (row & 7))*8);
        f16x8 vh = *(const f16x8*)&Vs[o];
        Oc[nt] = mfma16(ph, vh, Oc[nt]);
      }
    }
  }
  float inv[4];
  #pragma unroll
  for (int r = 0; r < 4; r++) inv[r] = 1.f / l_s[r];
  #pragma unroll
  for (int nt = 0; nt < 4; nt++){
    #pragma unroll
    for (int r = 0; r < 4; r++){
      int qa = qw + quad*4 + r;
      long o = (long)qa*DMODEL + h*64 + nt*16 + ln;
      attn_h[o] = f2h(Oc[nt][r] * inv[r]);
    }
  }
}

// ---------------- LayerNorm (fp32), optional fp16 copy ----------------
__global__ __launch_bounds__(256) void ln_kernel(const float* __restrict__ x,
    const float* __restrict__ g, const float* __restrict__ b,
    float* __restrict__ outF, unsigned short* __restrict__ outH){
  int s = blockIdx.x;
  const float* row = x + (long)s*DMODEL;
  int t = threadIdx.x;
  float v0 = row[t], v1 = row[t+256], v2 = row[t+512];
  float sum = v0+v1+v2;
  float sq  = v0*v0 + v1*v1 + v2*v2;
  for (int o = 32; o > 0; o >>= 1){ sum += __shfl_xor(sum, o); sq += __shfl_xor(sq, o); }
  __shared__ float s1[4], s2[4];
  int wv = t >> 6;
  if ((t & 63) == 0){ s1[wv] = sum; s2[wv] = sq; }
  __syncthreads();
  sum = s1[0]+s1[1]+s1[2]+s1[3];
  sq  = s2[0]+s2[1]+s2[2]+s2[3];
  float mean = sum * (1.0f/DMODEL);
  float var  = sq  * (1.0f/DMODEL) - mean*mean;
  float inv = rsqrtf(var + 1e-5f);
  float* orow = outF + (long)s*DMODEL;
  unsigned short* hrow = outH ? outH + (long)s*DMODEL : (unsigned short*)0;
  #pragma unroll
  for (int j = 0; j < 3; j++){
    int d = t + j*256;
    float y = (row[d] - mean) * inv * g[d] + b[d];
    orow[d] = y;
    if (hrow) hrow[d] = f2h(y);
  }
}

// ---------------- gate: wave-per-token GEMV, top-2 softmax. NO atomics. ----------------
__global__ __launch_bounds__(256) void gate_kernel(const float* __restrict__ x,
    const float* __restrict__ gw, const float* __restrict__ gb,
    float* __restrict__ gate_out, int* __restrict__ tok_e,
    float* __restrict__ tok_w){
  int w = threadIdx.x >> 6;
  int lane = threadIdx.x & 63;
  int s = blockIdx.x*4 + w;
  float acc[NEXP];
  #pragma unroll
  for (int e = 0; e < NEXP; e++) acc[e] = 0.f;
  const float* xr = x + (long)s*DMODEL;
  #pragma unroll
  for (int j = 0; j < DMODEL/64; j++){
    int d = lane + j*64;
    float xv = xr[d];
    const float* wr = gw + (long)d*NEXP;
    #pragma unroll
    for (int e = 0; e < NEXP; e++) acc[e] += xv * wr[e];
  }
  #pragma unroll
  for (int e = 0; e < NEXP; e++){
    float v = acc[e];
    for (int o = 32; o > 0; o >>= 1) v += __shfl_xor(v, o);
    acc[e] = v;
  }
  if (lane == 0){
    #pragma unroll
    for (int e = 0; e < NEXP; e++) acc[e] += gb[e];
    int i0 = 0;
    for (int e = 1; e < NEXP; e++) if (acc[e] > acc[i0]) i0 = e;
    int i1 = -1;
    for (int e = 0; e < NEXP; e++) if (e != i0 && (i1 < 0 || acc[e] > acc[i1])) i1 = e;
    float e1 = expf(acc[i1] - acc[i0]);
    float inv = 1.f / (1.f + e1);
    float w0 = inv, w1 = e1 * inv;
    float* go = gate_out + (long)s*NEXP;
    #pragma unroll
    for (int e = 0; e < NEXP; e++) go[e] = 0.f;
    go[i0] = w0; go[i1] = w1;
    tok_e[s*2] = i0; tok_e[s*2+1] = i1;
    tok_w[s*2] = w0; tok_w[s*2+1] = w1;
  }
}

// ---------------- route: single-block deterministic counting sort over 8192 slots ----------------
__global__ __launch_bounds__(256) void route_kernel(const int* __restrict__ tok_e,
    const float* __restrict__ tok_w,
    int* __restrict__ cnt, int* __restrict__ offs,
    int* __restrict__ pair_token, float* __restrict__ pair_w, int* __restrict__ tok_pi,
    int* __restrict__ tile_e, int* __restrict__ tile_m, int* __restrict__ ntiles){
  __shared__ int hist[256][NEXP];
  __shared__ int cntS[NEXP], offsS[NEXP];
  const int t = threadIdx.x;
  const int CH = NPAIR/256;   // 32 slots per thread
  const int base = t*CH;
  #pragma unroll
  for (int e = 0; e < NEXP; e++) hist[t][e] = 0;
  for (int i = 0; i < CH; i++)
    hist[t][tok_e[base+i]]++;
  __syncthreads();
  if (t < NEXP){
    int s = 0;
    for (int i = 0; i < 256; i++){ int v = hist[i][t]; hist[i][t] = s; s += v; }
    cntS[t] = s;
  }
  __syncthreads();
  if (t == 0){
    int s = 0, tt = 0;
    for (int e = 0; e < NEXP; e++){ offsS[e] = s; s += cntS[e]; }
    for (int e = 0; e < NEXP; e++)
      for (int m0 = 0; m0 < cntS[e]; m0 += 256){ tile_e[tt] = e; tile_m[tt] = m0; tt++; }
    *ntiles = tt;
    for (int e = 0; e < NEXP; e++){ cnt[e] = cntS[e]; offs[e] = offsS[e]; }
  }
  __syncthreads();
  for (int i = 0; i < CH; i++){
    int idx = base + i;
    int e = tok_e[idx];
    int pi = offsS[e] + hist[t][e]++;
    pair_token[pi] = idx >> 1;
    pair_w[pi] = tok_w[idx];
    tok_pi[idx] = pi;
  }
}

// ---------------- combine: moe[t] = w0*P[p0] + w1*P[p1] -> fp16 ----------------
__global__ __launch_bounds__(256) void combine_kernel(const float* __restrict__ Pbuf,
    const int* __restrict__ tok_pi, const float* __restrict__ tok_w,
    unsigned short* __restrict__ moe_h){
  int t = blockIdx.x;
  int d = threadIdx.x;
  float w0 = tok_w[t*2], w1 = tok_w[t*2+1];
  long p0 = (long)tok_pi[t*2]   * DMODEL;
  long p1 = (long)tok_pi[t*2+1] * DMODEL;
  unsigned short* orow = moe_h + (long)t*DMODEL;
  #pragma unroll
  for (int j = 0; j < 3; j++){
    int dd = d + j*256;
    orow[dd] = f2h(w0*Pbuf[p0+dd] + w1*Pbuf[p1+dd]);
  }
}

// ---------------- host launch ----------------
extern "C" void kernel_launch(void* const* d_in, const int* in_sizes, int n_in,
                              void* d_out, int out_size, void* d_ws, size_t ws_size,
                              hipStream_t stream){
  (void)in_sizes; (void)n_in; (void)out_size; (void)ws_size;
  const float* hidden = (const float*)d_in[0];
  const float* Wq  = (const float*)d_in[1];
  const float* bq  = (const float*)d_in[2];
  const float* Wk  = (const float*)d_in[3];
  const float* bk  = (const float*)d_in[4];
  const float* Wv  = (const float*)d_in[5];
  const float* bv  = (const float*)d_in[6];
  const float* Wo  = (const float*)d_in[7];
  const float* bo  = (const float*)d_in[8];
  const float* ln1g = (const float*)d_in[9];
  const float* ln1b = (const float*)d_in[10];
  const float* gateW = (const float*)d_in[11];
  const float* gateB = (const float*)d_in[12];
  const float* W1e = (const float*)d_in[13];
  const float* b1e = (const float*)d_in[14];
  const float* W2e = (const float*)d_in[15];
  const float* b2e = (const float*)d_in[16];
  const float* Wd  = (const float*)d_in[17];
  const float* bd  = (const float*)d_in[18];
  const float* ln2g = (const float*)d_in[19];
  const float* ln2b = (const float*)d_in[20];

  float* outL = (float*)d_out;
  float* outG = outL + (size_t)S_LEN*DMODEL;

  const size_t SD = (size_t)S_LEN*DMODEL;
  char* base = (char*)d_ws;
  size_t off = 0;
  auto alloc = [&](size_t bytes)->void*{
    void* r = base + off;
    off = (off + bytes + 255) & ~(size_t)255;
    return r;
  };
  unsigned short* x_h     = (unsigned short*)alloc(SD*2);
  unsigned short* wqkv_h  = (unsigned short*)alloc((size_t)2304*768*2);
  unsigned short* wo_h    = (unsigned short*)alloc((size_t)768*768*2);
  unsigned short* wd_h    = (unsigned short*)alloc((size_t)768*768*2);
  unsigned short* w1_h    = (unsigned short*)alloc((size_t)NEXP*FDIM*DMODEL*2);
  unsigned short* w2_h    = (unsigned short*)alloc((size_t)NEXP*FDIM*DMODEL*2);
  unsigned short* q_h   = (unsigned short*)alloc(SD*2);
  unsigned short* k_h   = (unsigned short*)alloc(SD*2);
  unsigned short* vt_h  = (unsigned short*)alloc(SD*2);
  unsigned short* attn_h = (unsigned short*)alloc(SD*2);
  float* preLN1    = (float*)alloc(SD*4);
  float* attnout_f = (float*)alloc(SD*4);
  unsigned short* attnout_h = (unsigned short*)alloc(SD*2);
  int*   tok_e = (int*)alloc(2*S_LEN*4);
  float* tok_w = (float*)alloc(2*S_LEN*4);
  int*   tok_pi = (int*)alloc(2*S_LEN*4);
  int*   cnt   = (int*)alloc(32*4);
  int*   offs  = (int*)alloc(32*4);
  int*   tile_e = (int*)alloc(MAXTILES*4);
  int*   tile_m = (int*)alloc(MAXTILES*4);
  int*   ntiles = (int*)alloc(4);
  int*   pair_token = (int*)alloc(NPAIR*4);
  float* pair_w     = (float*)alloc(NPAIR*4);
  unsigned short* Hbuf = (unsigned short*)alloc((size_t)NPAIR*FDIM*2);
  float* Pbuf = (float*)alloc((size_t)NPAIR*DMODEL*4);
  unsigned short* moe_h = (unsigned short*)alloc(SD*2);
  float* preLN2 = preLN1;

  // 1. hidden -> fp16
  split_kernel<<<dim3((unsigned)(SD/256)), dim3(256), 0, stream>>>(hidden, x_h, (int)SD);
  // 2. weight transposes/converts (all single-plane fp16)
  transp_kernel<<<dim3(24,24,1), dim3(32,8), 0, stream>>>(Wq, wqkv_h,           DMODEL, DMODEL, 0, 0);
  transp_kernel<<<dim3(24,24,1), dim3(32,8), 0, stream>>>(Wk, wqkv_h+768*768,   DMODEL, DMODEL, 0, 0);
  transp_kernel<<<dim3(24,24,1), dim3(32,8), 0, stream>>>(Wv, wqkv_h+2*768*768, DMODEL, DMODEL, 0, 0);
  transp_kernel<<<dim3(24,24,1), dim3(32,8), 0, stream>>>(Wo, wo_h, DMODEL, DMODEL, 0, 0);
  transp_kernel<<<dim3(24,24,1), dim3(32,8), 0, stream>>>(Wd, wd_h, DMODEL, DMODEL, 0, 0);
  transp_kernel<<<dim3(96,24,NEXP), dim3(32,8), 0, stream>>>(W1e, w1_h, DMODEL, FDIM, (long)DMODEL*FDIM, (long)DMODEL*FDIM);
  transp_kernel<<<dim3(24,96,NEXP), dim3(32,8), 0, stream>>>(W2e, w2_h, FDIM, DMODEL, (long)DMODEL*FDIM, (long)DMODEL*FDIM);

  // 3. QKV projection -> Q,K [h][s][64]; V transposed [h][d][s]  (fp16)
  GemmP pq = {};
  pq.A = x_h; pq.B = wqkv_h;
  pq.M = S_LEN; pq.N = 2304; pq.K = DMODEL;
  pq.bias = bq; pq.bias2 = bk; pq.bias3 = bv;
  pq.qh = q_h; pq.kh = k_h; pq.vth = vt_h;
  gemm_bt<0><<<dim3(18,32,1), dim3(256), 0, stream>>>(pq);

  // 4. MFMA attention -> attn fp16
  attn_mfma<<<dim3(16,NHEADS,4), dim3(256), 0, stream>>>(q_h, k_h, vt_h, attn_h);

  // 5. Wo projection + bias + residual -> preLN1 (fp32)
  GemmP pw = {};
  pw.A = attn_h; pw.B = wo_h;
  pw.M = S_LEN; pw.N = DMODEL; pw.K = DMODEL;
  pw.bias = bo; pw.resid = hidden; pw.outF = preLN1;
  gemm_bt<1><<<dim3(6,32,1), dim3(256), 0, stream>>>(pw);

  // 6. LN1 -> attnout (fp32 + fp16)
  ln_kernel<<<dim3(S_LEN), dim3(256), 0, stream>>>(preLN1, ln1g, ln1b, attnout_f, attnout_h);

  // 7. gate (no atomics) + deterministic route
  gate_kernel<<<dim3(S_LEN/4), dim3(256), 0, stream>>>(attnout_f, gateW, gateB, outG, tok_e, tok_w);
  route_kernel<<<dim3(1), dim3(256), 0, stream>>>(tok_e, tok_w, cnt, offs,
      pair_token, pair_w, tok_pi, tile_e, tile_m, ntiles);

  // 8. MoE expert GEMMs (top-2 sparse), compacted tiles
  GemmP p1 = {};
  p1.A = attnout_h; p1.B = w1_h; p1.M = S_LEN; p1.N = FDIM; p1.K = DMODEL;
  p1.bias = b1e; p1.outBF = Hbuf;
  p1.pair_token = pair_token; p1.cnt = cnt; p1.offs = offs;
  p1.tile_e = tile_e; p1.tile_m = tile_m; p1.ntiles = ntiles;
  gemm_big<2><<<dim3(24,MAXTILES), dim3(512), 0, stream>>>(p1);

  GemmP p2 = {};
  p2.A = Hbuf; p2.B = w2_h; p2.M = S_LEN; p2.N = DMODEL; p2.K = FDIM;
  p2.bias = b2e; p2.outF = Pbuf;
  p2.pair_token = pair_token; p2.pair_w = pair_w; p2.cnt = cnt; p2.offs = offs;
  p2.tile_e = tile_e; p2.tile_m = tile_m; p2.ntiles = ntiles;
  gemm_big<3><<<dim3(6,MAXTILES), dim3(512), 0, stream>>>(p2);

  // 9. combine pairs -> moe fp16; Wd + bias + residual(attention_output) -> preLN2
  combine_kernel<<<dim3(S_LEN), dim3(256), 0, stream>>>(Pbuf, tok_pi, tok_w, moe_h);
  GemmP pd = {};
  pd.A = moe_h; pd.B = wd_h; pd.M = S_LEN; pd.N = DMODEL; pd.K = DMODEL;
  pd.bias = bd; pd.resid = attnout_f; pd.outF = preLN2;
  gemm_bt<4><<<dim3(6,32,1), dim3(256), 0, stream>>>(pd);

  // 10. LN2 -> layer_output
  ln_kernel<<<dim3(S_LEN), dim3(256), 0, stream>>>(preLN2, ln2g, ln2b, outL, nullptr);
}